// Round 14
// baseline (137.613 us; speedup 1.0000x reference)
//
#include <hip/hip_runtime.h>
#include <hip/hip_bf16.h>
#include <stdint.h>

typedef __attribute__((ext_vector_type(8))) short bf16x8;
typedef __attribute__((ext_vector_type(4))) float f32x4;

#define DEVI static __device__ __forceinline__

// Problem sizes (fixed)
static constexpr int B_SZ = 4096, N_SZ = 128, H_SZ = 128, W_SZ = 64;

// ws layout (bytes), all 16B aligned
static constexpr size_t OFF_W1 = 0;                      // 128 * 128*128 bf16 = 4 MB (UNswizzled [n][c][h])
static constexpr size_t OFF_W2 = OFF_W1 + 4194304;       // 128 * 64*128 bf16 = 2 MB (UNswizzled [n][w][k])
static constexpr size_t OFF_F1 = OFF_W2 + 2097152;       // (unused)
static constexpr size_t OFF_F2 = OFF_F1 + 32768;         // 384*128 bf16 = 96 KB (swizzled [o][j])
static constexpr size_t OFF_H  = OFF_F2 + 98304;         // 64 tiles x 16KB bf16 (swizzled 64-row h tiles)

DEVI unsigned short f2bf(float f) {
  union { __hip_bfloat16 b; unsigned short u; } cv;
  cv.b = __float2bfloat16(f);
  return cv.u;
}
DEVI float bf2f(unsigned short u) {
  union { unsigned int i; float f; } cv;
  cv.i = ((unsigned int)u) << 16;
  return cv.f;
}

// Raw workgroup barrier: execution sync + LDS visibility (lgkmcnt), but does NOT
// drain vmcnt -> global prefetch loads stay in flight across it.
DEVI void bar_lds() {
  __builtin_amdgcn_sched_barrier(0);
  asm volatile("s_waitcnt lgkmcnt(0)" ::: "memory");
  __builtin_amdgcn_s_barrier();
  __builtin_amdgcn_sched_barrier(0);
}

// Read one MFMA fragment (8 contiguous bf16 along k) from a swizzled tile
// (LDS or global). Row stride 256B; 16B slot s stored at (s ^ (row&7)).
DEVI bf16x8 frag_ld(const unsigned char* base, int row, int kslot) {
  return *reinterpret_cast<const bf16x8*>(base + row * 256 + (((kslot ^ (row & 7)) << 4)));
}
// Unswizzled fragment read (global memory, 256B rows).
DEVI bf16x8 gfrag_ld(const unsigned char* base, int row, int kslot) {
  return *reinterpret_cast<const bf16x8*>(base + row * 256 + (kslot << 4));
}

// Stage an nrows x 128 fp32 tile (row stride in elems) into swizzled bf16 LDS.
DEVI void stage_f32_tile(const float* src, int row_stride, unsigned char* dst, int tid, int nrows) {
  for (int t = tid; t < nrows * 16; t += 256) {
    int row = t >> 4, s = t & 15;
    const float* p = src + (size_t)row * row_stride + s * 8;
    union { unsigned short u[8]; uint4 v; } pk;
#pragma unroll
    for (int j = 0; j < 8; ++j) pk.u[j] = f2bf(p[j]);
    *reinterpret_cast<uint4*>(dst + row * 256 + ((s ^ (row & 7)) << 4)) = pk.v;
  }
}

// ================ K1: prep (W1,W2,F2s,logits) || f1 (h = relu(emb@fc1^T+b1)) ================
__global__ __launch_bounds__(256) void prep_f1_kernel(const float* __restrict__ rw1,
                                                      const float* __restrict__ rw2,
                                                      const float* __restrict__ fc2w,
                                                      const float* __restrict__ slog,
                                                      const float* __restrict__ emb,
                                                      const float* __restrict__ fc1w,
                                                      const float* __restrict__ fc1b,
                                                      float* __restrict__ out,
                                                      unsigned char* __restrict__ ws) {
  __shared__ unsigned char sA[16384];  // f1: emb 64-row tile
  __shared__ unsigned char sB[32768];  // f1: fc1w tile

  const int bid = blockIdx.x;
  const int tid = threadIdx.x;
  if (bid < 2072) {
    const int T_W1 = 128 * 128 * 16;  // (n,s,c): W1t[n][c][h=s*8+j] = rw1[n][h][c]
    const int T_W2 = 128 * 64 * 16;   // (n,s,w): W2t[n][w][k=s*8+j] = rw2[n][k][w]
    const int T_F2 = 384 * 16;        // (o,s):   F2s[o][j] = fc2w[o][j]  (swizzled)
    int id = bid * 256 + tid;
    if (id < T_W1) {
      int c = id & 127, rest = id >> 7;
      int s = rest & 15, n = rest >> 4;
      const float* src = rw1 + (size_t)n * 16384 + (size_t)(s * 8) * 128 + c;
      union { unsigned short u[8]; uint4 v; } pk;
#pragma unroll
      for (int j = 0; j < 8; ++j) pk.u[j] = f2bf(src[(size_t)j * 128]);
      size_t dst = OFF_W1 + ((size_t)n * 128 + c) * 256 + (size_t)(s << 4);
      *reinterpret_cast<uint4*>(ws + dst) = pk.v;
      return;
    }
    id -= T_W1;
    if (id < T_W2) {
      int w = id & 63, rest = id >> 6;
      int s = rest & 15, n = rest >> 4;
      const float* src = rw2 + (size_t)n * 8192 + (size_t)(s * 8) * 64 + w;
      union { unsigned short u[8]; uint4 v; } pk;
#pragma unroll
      for (int j = 0; j < 8; ++j) pk.u[j] = f2bf(src[(size_t)j * 64]);
      size_t dst = OFF_W2 + ((size_t)n * 64 + w) * 256 + (size_t)(s << 4);
      *reinterpret_cast<uint4*>(ws + dst) = pk.v;
      return;
    }
    id -= T_W2;
    if (id < T_F2) {
      int s = id & 15, o = id >> 4;
      const float* src = fc2w + (size_t)o * 128 + s * 8;
      union { unsigned short u[8]; uint4 v; } pk;
#pragma unroll
      for (int j = 0; j < 8; ++j) pk.u[j] = f2bf(src[j]);
      *reinterpret_cast<uint4*>(ws + OFF_F2 + (size_t)o * 256 + ((s ^ (o & 7)) << 4)) = pk.v;
      return;
    }
    id -= T_F2;
    // logits passthrough: 2MB as uint4
    reinterpret_cast<uint4*>(out)[id] = reinterpret_cast<const uint4*>(slog)[id];
    return;
  }

  // ---- f1 path: 64 blocks x 64 b-rows ----
  const int bt = bid - 2072;
  const int b0 = bt * 64;
  stage_f32_tile(fc1w, 128, sB, tid, 128);
  stage_f32_tile(emb + (size_t)b0 * 128, 128, sA, tid, 64);
  __syncthreads();

  const int wave = tid >> 6, lane = tid & 63;
  const int wm = wave >> 1, wn = wave & 1;
  const int lr = lane & 15, lk = lane >> 4;

  f32x4 acc[2][4] = {};
#pragma unroll
  for (int kk = 0; kk < 4; ++kk) {
    const int slot = kk * 4 + lk;
    bf16x8 af[2], bfv[4];
#pragma unroll
    for (int m = 0; m < 2; ++m) af[m] = frag_ld(sA, wm * 32 + m * 16 + lr, slot);
#pragma unroll
    for (int q = 0; q < 4; ++q) bfv[q] = frag_ld(sB, wn * 64 + q * 16 + lr, slot);
#pragma unroll
    for (int m = 0; m < 2; ++m)
#pragma unroll
      for (int q = 0; q < 4; ++q)
        acc[m][q] = __builtin_amdgcn_mfma_f32_16x16x32_bf16(af[m], bfv[q], acc[m][q], 0, 0, 0);
  }

  unsigned char* tile = ws + OFF_H + (size_t)bt * 16384;
#pragma unroll
  for (int q = 0; q < 4; ++q) {
    int c = wn * 64 + q * 16 + lr;
    float bias = fc1b[c];
#pragma unroll
    for (int m = 0; m < 2; ++m) {
#pragma unroll
      for (int j = 0; j < 4; ++j) {
        int r = wm * 32 + m * 16 + lk * 4 + j;
        float v = acc[m][q][j] + bias;
        v = v > 0.f ? v : 0.f;
        *reinterpret_cast<unsigned short*>(tile + r * 256 + ((c * 2) ^ ((r & 7) << 4))) = f2bf(v);
      }
    }
  }
}

// ================ K2: recon (1024 blocks) || f2 (192 blocks) ================
// recon: v13 structure (W1 persistent VGPR, W2 re-read/iter, separate sHN,
// biases in LDS, sOUT coalesced flush, 2 non-draining barriers/iter, (256,2))
// with DOUBLE-DEPTH register staging: two fra/frb sets; tiles t+1 AND t+2 in
// flight; iter t consumes set[t&1] at wpref then re-issues tile t+3 into it.
// Issue->use distance ~2 iters (2x HBM latency margin).
// Hazards unchanged: epi1(t) w:sHN vs G2(t-1) r:sHN -- [C](t); wpref(t) w:bufn
// vs G1(t+1) r:bufn -- [F](t); epi2(t) w:sOUT vs flush(t) r:sOUT -- [C](t+1);
// flush(t-1) r:sOUT vs epi2(t) w:sOUT -- [F](t).
__global__ __launch_bounds__(256, 2) void recon_f2_kernel(const float* __restrict__ se,
                                                          const float* __restrict__ rb1,
                                                          const float* __restrict__ rb2,
                                                          const float* __restrict__ fc2b,
                                                          const unsigned char* __restrict__ ws,
                                                          float* __restrict__ out3,
                                                          float* __restrict__ out2) {
  __shared__ unsigned char smem[59136];

  const int bid = blockIdx.x;
  const int tid = threadIdx.x;
  const int wave = tid >> 6, lane = tid & 63;
  const int lr = lane & 15, lk = lane >> 4;

  if (bid >= 1024) {
    // ---- f2 path: 192 blocks (bt 0..63 x ch 0..2), 64 b-rows each ----
    const int fid = bid - 1024;
    const int bt = fid & 63, ch = fid >> 6;
    const int b0 = bt * 64;
    unsigned char* sB = smem;  // 32KB F2s chunk
    {
      const uint4* bp = reinterpret_cast<const uint4*>(ws + OFF_F2 + (size_t)ch * 32768);
      uint4* db = reinterpret_cast<uint4*>(sB);
      for (int c = tid; c < 2048; c += 256) db[c] = bp[c];
    }
    __syncthreads();

    const int wm = wave >> 1, wn = wave & 1;
    const unsigned char* htile = ws + OFF_H + (size_t)bt * 16384;

    f32x4 acc[2][4] = {};
#pragma unroll
    for (int kk = 0; kk < 4; ++kk) {
      const int slot = kk * 4 + lk;
      bf16x8 af[2], bfv[4];
#pragma unroll
      for (int m = 0; m < 2; ++m) af[m] = frag_ld(htile, wm * 32 + m * 16 + lr, slot);
#pragma unroll
      for (int q = 0; q < 4; ++q) bfv[q] = frag_ld(sB, wn * 64 + q * 16 + lr, slot);
#pragma unroll
      for (int m = 0; m < 2; ++m)
#pragma unroll
        for (int q = 0; q < 4; ++q)
          acc[m][q] = __builtin_amdgcn_mfma_f32_16x16x32_bf16(af[m], bfv[q], acc[m][q], 0, 0, 0);
    }

#pragma unroll
    for (int q = 0; q < 4; ++q) {
      int o = ch * 128 + wn * 64 + q * 16 + lr;
      float bias = fc2b[o];
#pragma unroll
      for (int m = 0; m < 2; ++m) {
#pragma unroll
        for (int j = 0; j < 4; ++j) {
          int r = wm * 32 + m * 16 + lk * 4 + j;
          out2[(size_t)(b0 + r) * 384 + o] = acc[m][q][j] + bias;
        }
      }
    }
    return;
  }

  // ---- recon path ----
  unsigned char* sSE0 = smem;                              // 16KB
  unsigned char* sSE1 = smem + 16384;                      // 16KB
  unsigned char* sHN  = smem + 32768;                      // 16KB
  unsigned char* sOUT = smem + 49152;                      // 64 x 72 bf16 = 9216B (padded rows)
  float* sBIAS = reinterpret_cast<float*>(smem + 58368);   // [0..127] rb1, [128..191] rb2

  const int n = bid & 127;   // linear id % 8 == n % 8 -> same-n blocks share XCD
  const int btg = bid >> 7;  // 0..7
  const int b0 = btg * 512;

  const int wm = wave >> 1, wq = wave & 1;  // wm: out-row half, wq: b half (32 each)

  // W1 A-fragments (loop-invariant -> VGPR, 64 regs)
  const unsigned char* w1b = ws + OFF_W1 + (size_t)n * 32768;
  const unsigned char* w2b = ws + OFF_W2 + (size_t)n * 16384;
  bf16x8 w1f[4][4];
#pragma unroll
  for (int m = 0; m < 4; ++m)
#pragma unroll
    for (int kk = 0; kk < 4; ++kk)
      w1f[m][kk] = gfrag_ld(w1b, wm * 64 + m * 16 + lr, kk * 4 + lk);

  // biases -> LDS stub (no VGPR held across phases)
  if (tid < 192)
    sBIAS[tid] = (tid < 128) ? rb1[(size_t)n * 128 + tid] : rb2[(size_t)n * 64 + tid - 128];

  // stage SE subtile 0 directly
  stage_f32_tile(se + ((size_t)b0 * 128 + n) * 128, 128 * 128, sSE0, tid, 64);
  unsigned short* outus = reinterpret_cast<unsigned short*>(out3);

  // per-iter tmp flush: 4 threads per b-row, each moves 32B (2x uint4) ->
  // one full 128B contiguous line per (b,n) row.
  const int fb = tid >> 2, fqt = tid & 3;
  auto flush_out = [&](int tt) {
    uint4 v0 = *reinterpret_cast<const uint4*>(sOUT + fb * 144 + fqt * 32);
    uint4 v1 = *reinterpret_cast<const uint4*>(sOUT + fb * 144 + fqt * 32 + 16);
    unsigned short* dst = outus + (size_t)(b0 + tt * 64 + fb) * 16384 + 8192 + n * 64 + fqt * 16;
    *reinterpret_cast<uint4*>(dst) = v0;
    *reinterpret_cast<uint4*>(dst + 8) = v1;
  };

  // DOUBLE-DEPTH staging: two register sets; set[p] holds tile (t+1) when t&1==p.
  float4 fA0[4], fB0[4], fA1[4], fB1[4];
  const int prow = tid >> 4, ps = tid & 15;  // each thread's fixed (row, slot) in a tile
  auto issue_into = [&](int tile, float4* fa, float4* fb) {
    const float* sb = se + ((size_t)(b0 + tile * 64) * 128 + n) * 128;
#pragma unroll
    for (int k = 0; k < 4; ++k) {
      const float* p = sb + (size_t)(prow + k * 16) * 16384 + ps * 8;
      fa[k] = *reinterpret_cast<const float4*>(p);
      fb[k] = *reinterpret_cast<const float4*>(p + 4);
    }
  };
  auto write_from = [&](unsigned char* dst, const float4* fa, const float4* fb) {
#pragma unroll
    for (int k = 0; k < 4; ++k) {
      const int row = prow + k * 16;
      union { unsigned short u[8]; uint4 v; } pk;
#pragma unroll
      for (int j = 0; j < 4; ++j) pk.u[j] = f2bf(fa[k][j]);
#pragma unroll
      for (int j = 0; j < 4; ++j) pk.u[4 + j] = f2bf(fb[k][j]);
      *reinterpret_cast<uint4*>(dst + row * 256 + ((ps ^ (row & 7)) << 4)) = pk.v;
    }
  };

  // prologue: issue loads for tiles 1 (set0) and 2 (set1)
  issue_into(1, fA0, fB0);
  issue_into(2, fA1, fB1);
  bar_lds();  // tile 0 + biases staged (no vmcnt drain: prefetches stay in flight)

#pragma unroll 1
  for (int t = 0; t < 8; ++t) {
    unsigned char* bufc = (t & 1) ? sSE1 : sSE0;
    unsigned char* bufn = (t & 1) ? sSE0 : sSE1;

    // GEMM1': 128(h_out) x 64(b) x 128(k); wave owns 64 x 32
    f32x4 acc[4][2] = {};
#pragma unroll
    for (int kk = 0; kk < 4; ++kk) {
      const int slot = kk * 4 + lk;
      bf16x8 bv[2];
#pragma unroll
      for (int q = 0; q < 2; ++q) bv[q] = frag_ld(bufc, wq * 32 + q * 16 + lr, slot);
#pragma unroll
      for (int m = 0; m < 4; ++m)
#pragma unroll
        for (int q = 0; q < 2; ++q)
          acc[m][q] = __builtin_amdgcn_mfma_f32_16x16x32_bf16(w1f[m][kk], bv[q], acc[m][q], 0, 0, 0);
    }
    bar_lds();  // [C] G1 reads of bufc done; prev epi2's sOUT writes visible; prev G2's sHN reads done

    // write prefetched SE(t+1) from set[t&1], then immediately re-issue tile t+3 into it
    if (t < 7) {
      if (t & 1) write_from(bufn, fA1, fB1);
      else       write_from(bufn, fA0, fB0);
    }
    if (t < 5) {
      if (t & 1) issue_into(t + 3, fA1, fB1);
      else       issue_into(t + 3, fA0, fB0);
    }

    // flush previous tile's output from sOUT (reads sealed from epi2(t) by [F](t))
    if (t > 0) flush_out(t - 1);

    // W2 A-fragments: re-read from L2 each iter (same addr -> hot); used after [F]
    bf16x8 w2f[2][4];
#pragma unroll
    for (int m = 0; m < 2; ++m)
#pragma unroll
      for (int kk = 0; kk < 4; ++kk)
        w2f[m][kk] = gfrag_ld(w2b, wm * 32 + m * 16 + lr, kk * 4 + lk);

    // epilogue1: hn[b][k] = relu(C1t[k][b] + rb1[k]) -> bf16 into sHN (bias from LDS)
#pragma unroll
    for (int m = 0; m < 4; ++m) {
      const int k0 = wm * 64 + m * 16 + lk * 4;
      const int s16 = k0 >> 3, half = (k0 >> 2) & 1;
      union { float4 v; float f[4]; } b1;
      b1.v = *reinterpret_cast<const float4*>(sBIAS + k0);
#pragma unroll
      for (int q = 0; q < 2; ++q) {
        const int b = wq * 32 + q * 16 + lr;
        union { unsigned short u[4]; uint2 v; } pk;
#pragma unroll
        for (int j = 0; j < 4; ++j) {
          float v = acc[m][q][j] + b1.f[j];
          v = v > 0.f ? v : 0.f;
          pk.u[j] = f2bf(v);
        }
        *reinterpret_cast<uint2*>(sHN + b * 256 + ((s16 ^ (b & 7)) << 4) + half * 8) = pk.v;
      }
    }
    bar_lds();  // [F] sHN + bufn ready; flush(t-1) reads sealed before epi2(t)

    // GEMM2': 64(w) x 64(b) x 128(k); wave owns 32 x 32
    f32x4 acc2[2][2] = {};
#pragma unroll
    for (int kk = 0; kk < 4; ++kk) {
      const int slot = kk * 4 + lk;
      bf16x8 bv[2];
#pragma unroll
      for (int q = 0; q < 2; ++q) bv[q] = frag_ld(sHN, wq * 32 + q * 16 + lr, slot);
#pragma unroll
      for (int m = 0; m < 2; ++m)
#pragma unroll
        for (int q = 0; q < 2; ++q)
          acc2[m][q] = __builtin_amdgcn_mfma_f32_16x16x32_bf16(w2f[m][kk], bv[q], acc2[m][q], 0, 0, 0);
    }

    // epilogue2: bf16 into sOUT[b][w] (padded rows 144B)
#pragma unroll
    for (int m = 0; m < 2; ++m) {
      const int w0 = wm * 32 + m * 16 + lk * 4;
      union { float4 v; float f[4]; } b2;
      b2.v = *reinterpret_cast<const float4*>(sBIAS + 128 + w0);
#pragma unroll
      for (int q = 0; q < 2; ++q) {
        const int bloc = wq * 32 + q * 16 + lr;
        union { unsigned short u[4]; uint2 v; } pk;
#pragma unroll
        for (int j = 0; j < 4; ++j) pk.u[j] = f2bf(acc2[m][q][j] + b2.f[j]);
        *reinterpret_cast<uint2*>(sOUT + bloc * 144 + w0 * 2) = pk.v;
      }
    }
    // no closing barrier: epi2(t) w:sOUT vs flush(t) r:sOUT split by [C](t+1).
  }
  bar_lds();       // seal epi2(7)'s sOUT writes
  flush_out(7);    // final tile flush
}

// ================ K3: transpose tmp bf16 [b][n][w] -> out3 fp32 [b][w][n] ================
__global__ __launch_bounds__(256) void transpose_kernel(float* __restrict__ out3) {
  const int b = blockIdx.x, wave = threadIdx.x >> 6, lane = threadIdx.x & 63;
  const unsigned short* t = reinterpret_cast<const unsigned short*>(out3) + (size_t)b * 16384 + 8192;
  float* dst = out3 + (size_t)b * 8192;
  uint4 r[2][2];
#pragma unroll
  for (int half = 0; half < 2; ++half) {
    const int g = half * 4 + wave;
    r[half][0] = *reinterpret_cast<const uint4*>(t + lane * 64 + g * 8);
    r[half][1] = *reinterpret_cast<const uint4*>(t + (size_t)(lane + 64) * 64 + g * 8);
  }
  __syncthreads();  // all reads done before dst writes clobber the tmp region
#pragma unroll
  for (int half = 0; half < 2; ++half) {
    const int g = half * 4 + wave;
    union { uint4 v; unsigned short u[8]; } p0, p1;
    p0.v = r[half][0];
    p1.v = r[half][1];
#pragma unroll
    for (int j = 0; j < 8; ++j) {
      dst[(g * 8 + j) * 128 + lane] = bf2f(p0.u[j]);
      dst[(g * 8 + j) * 128 + lane + 64] = bf2f(p1.u[j]);
    }
  }
}

extern "C" void kernel_launch(void* const* d_in, const int* in_sizes, int n_in,
                              void* d_out, int out_size, void* d_ws, size_t ws_size,
                              hipStream_t stream) {
  const float* emb  = (const float*)d_in[0];
  const float* se   = (const float*)d_in[1];
  const float* slog = (const float*)d_in[2];
  const float* fc1w = (const float*)d_in[3];
  const float* fc1b = (const float*)d_in[4];
  const float* fc2w = (const float*)d_in[5];
  const float* fc2b = (const float*)d_in[6];
  const float* rw1  = (const float*)d_in[7];
  const float* rb1  = (const float*)d_in[8];
  const float* rw2  = (const float*)d_in[9];
  const float* rb2  = (const float*)d_in[10];
  float* out = (float*)d_out;
  unsigned char* ws = (unsigned char*)d_ws;

  float* out2 = out + (size_t)B_SZ * N_SZ;
  float* out3 = out2 + (size_t)B_SZ * 384;

  // K1: weight prep + logits copy || forecast stage 1
  prep_f1_kernel<<<2136, 256, 0, stream>>>(rw1, rw2, fc2w, slog, emb, fc1w, fc1b, out, ws);

  // K2: reconstruction (dominant) || forecast stage 2
  recon_f2_kernel<<<1216, 256, 0, stream>>>(se, rb1, rb2, fc2b, ws, out3, out2);

  // K3: transpose to final [b][w][n] fp32
  transpose_kernel<<<4096, 256, 0, stream>>>(out3);
}

// Round 15
// 136.724 us; speedup vs baseline: 1.0065x; 1.0065x over previous
//
#include <hip/hip_runtime.h>
#include <hip/hip_bf16.h>
#include <stdint.h>

typedef __attribute__((ext_vector_type(8))) short bf16x8;
typedef __attribute__((ext_vector_type(4))) float f32x4;

#define DEVI static __device__ __forceinline__

// Problem sizes (fixed)
static constexpr int B_SZ = 4096, N_SZ = 128, H_SZ = 128, W_SZ = 64;

// ws layout (bytes), all 16B aligned
static constexpr size_t OFF_W1 = 0;                      // 128 * 128*128 bf16 = 4 MB (UNswizzled [n][c][h])
static constexpr size_t OFF_W2 = OFF_W1 + 4194304;       // 128 * 64*128 bf16 = 2 MB (UNswizzled [n][w][k])
static constexpr size_t OFF_F1 = OFF_W2 + 2097152;       // (unused)
static constexpr size_t OFF_F2 = OFF_F1 + 32768;         // 384*128 bf16 = 96 KB (swizzled [o][j])
static constexpr size_t OFF_H  = OFF_F2 + 98304;         // 64 tiles x 16KB bf16 (swizzled 64-row h tiles)

DEVI unsigned short f2bf(float f) {
  union { __hip_bfloat16 b; unsigned short u; } cv;
  cv.b = __float2bfloat16(f);
  return cv.u;
}
DEVI float bf2f(unsigned short u) {
  union { unsigned int i; float f; } cv;
  cv.i = ((unsigned int)u) << 16;
  return cv.f;
}

// Raw workgroup barrier: execution sync + LDS visibility (lgkmcnt), but does NOT
// drain vmcnt -> global prefetch loads stay in flight across it.
DEVI void bar_lds() {
  __builtin_amdgcn_sched_barrier(0);
  asm volatile("s_waitcnt lgkmcnt(0)" ::: "memory");
  __builtin_amdgcn_s_barrier();
  __builtin_amdgcn_sched_barrier(0);
}

// Read one MFMA fragment (8 contiguous bf16 along k) from a swizzled tile
// (LDS or global). Row stride 256B; 16B slot s stored at (s ^ (row&7)).
DEVI bf16x8 frag_ld(const unsigned char* base, int row, int kslot) {
  return *reinterpret_cast<const bf16x8*>(base + row * 256 + (((kslot ^ (row & 7)) << 4)));
}
// Unswizzled fragment read (global memory, 256B rows).
DEVI bf16x8 gfrag_ld(const unsigned char* base, int row, int kslot) {
  return *reinterpret_cast<const bf16x8*>(base + row * 256 + (kslot << 4));
}

// Stage an nrows x 128 fp32 tile (row stride in elems) into swizzled bf16 LDS.
DEVI void stage_f32_tile(const float* src, int row_stride, unsigned char* dst, int tid, int nrows) {
  for (int t = tid; t < nrows * 16; t += 256) {
    int row = t >> 4, s = t & 15;
    const float* p = src + (size_t)row * row_stride + s * 8;
    union { unsigned short u[8]; uint4 v; } pk;
#pragma unroll
    for (int j = 0; j < 8; ++j) pk.u[j] = f2bf(p[j]);
    *reinterpret_cast<uint4*>(dst + row * 256 + ((s ^ (row & 7)) << 4)) = pk.v;
  }
}

// ================ K1: prep (W1,W2,F2s,logits) || f1 (h = relu(emb@fc1^T+b1)) ================
__global__ __launch_bounds__(256) void prep_f1_kernel(const float* __restrict__ rw1,
                                                      const float* __restrict__ rw2,
                                                      const float* __restrict__ fc2w,
                                                      const float* __restrict__ slog,
                                                      const float* __restrict__ emb,
                                                      const float* __restrict__ fc1w,
                                                      const float* __restrict__ fc1b,
                                                      float* __restrict__ out,
                                                      unsigned char* __restrict__ ws) {
  __shared__ unsigned char sA[16384];  // f1: emb 64-row tile
  __shared__ unsigned char sB[32768];  // f1: fc1w tile

  const int bid = blockIdx.x;
  const int tid = threadIdx.x;
  if (bid < 2072) {
    const int T_W1 = 128 * 128 * 16;  // (n,s,c): W1t[n][c][h=s*8+j] = rw1[n][h][c]
    const int T_W2 = 128 * 64 * 16;   // (n,s,w): W2t[n][w][k=s*8+j] = rw2[n][k][w]
    const int T_F2 = 384 * 16;        // (o,s):   F2s[o][j] = fc2w[o][j]  (swizzled)
    int id = bid * 256 + tid;
    if (id < T_W1) {
      int c = id & 127, rest = id >> 7;
      int s = rest & 15, n = rest >> 4;
      const float* src = rw1 + (size_t)n * 16384 + (size_t)(s * 8) * 128 + c;
      union { unsigned short u[8]; uint4 v; } pk;
#pragma unroll
      for (int j = 0; j < 8; ++j) pk.u[j] = f2bf(src[(size_t)j * 128]);
      size_t dst = OFF_W1 + ((size_t)n * 128 + c) * 256 + (size_t)(s << 4);
      *reinterpret_cast<uint4*>(ws + dst) = pk.v;
      return;
    }
    id -= T_W1;
    if (id < T_W2) {
      int w = id & 63, rest = id >> 6;
      int s = rest & 15, n = rest >> 4;
      const float* src = rw2 + (size_t)n * 8192 + (size_t)(s * 8) * 64 + w;
      union { unsigned short u[8]; uint4 v; } pk;
#pragma unroll
      for (int j = 0; j < 8; ++j) pk.u[j] = f2bf(src[(size_t)j * 64]);
      size_t dst = OFF_W2 + ((size_t)n * 64 + w) * 256 + (size_t)(s << 4);
      *reinterpret_cast<uint4*>(ws + dst) = pk.v;
      return;
    }
    id -= T_W2;
    if (id < T_F2) {
      int s = id & 15, o = id >> 4;
      const float* src = fc2w + (size_t)o * 128 + s * 8;
      union { unsigned short u[8]; uint4 v; } pk;
#pragma unroll
      for (int j = 0; j < 8; ++j) pk.u[j] = f2bf(src[j]);
      *reinterpret_cast<uint4*>(ws + OFF_F2 + (size_t)o * 256 + ((s ^ (o & 7)) << 4)) = pk.v;
      return;
    }
    id -= T_F2;
    // logits passthrough: 2MB as uint4
    reinterpret_cast<uint4*>(out)[id] = reinterpret_cast<const uint4*>(slog)[id];
    return;
  }

  // ---- f1 path: 64 blocks x 64 b-rows ----
  const int bt = bid - 2072;
  const int b0 = bt * 64;
  stage_f32_tile(fc1w, 128, sB, tid, 128);
  stage_f32_tile(emb + (size_t)b0 * 128, 128, sA, tid, 64);
  __syncthreads();

  const int wave = tid >> 6, lane = tid & 63;
  const int wm = wave >> 1, wn = wave & 1;
  const int lr = lane & 15, lk = lane >> 4;

  f32x4 acc[2][4] = {};
#pragma unroll
  for (int kk = 0; kk < 4; ++kk) {
    const int slot = kk * 4 + lk;
    bf16x8 af[2], bfv[4];
#pragma unroll
    for (int m = 0; m < 2; ++m) af[m] = frag_ld(sA, wm * 32 + m * 16 + lr, slot);
#pragma unroll
    for (int q = 0; q < 4; ++q) bfv[q] = frag_ld(sB, wn * 64 + q * 16 + lr, slot);
#pragma unroll
    for (int m = 0; m < 2; ++m)
#pragma unroll
      for (int q = 0; q < 4; ++q)
        acc[m][q] = __builtin_amdgcn_mfma_f32_16x16x32_bf16(af[m], bfv[q], acc[m][q], 0, 0, 0);
  }

  unsigned char* tile = ws + OFF_H + (size_t)bt * 16384;
#pragma unroll
  for (int q = 0; q < 4; ++q) {
    int c = wn * 64 + q * 16 + lr;
    float bias = fc1b[c];
#pragma unroll
    for (int m = 0; m < 2; ++m) {
#pragma unroll
      for (int j = 0; j < 4; ++j) {
        int r = wm * 32 + m * 16 + lk * 4 + j;
        float v = acc[m][q][j] + bias;
        v = v > 0.f ? v : 0.f;
        *reinterpret_cast<unsigned short*>(tile + r * 256 + ((c * 2) ^ ((r & 7) << 4))) = f2bf(v);
      }
    }
  }
}

// ================ K2: recon ONLY (1024 blocks = exactly 2.0 occupancy rounds) ================
// v13 structure unchanged: W1 persistent VGPR, W2 re-read/iter, separate sHN,
// biases in LDS, sOUT coalesced flush, 2 non-draining barriers/iter, (256,2).
// f2 moved to K3 -> no partial third round (was 1216/512 = 2.375 rounds).
// Hazards: epi1(t) w:sHN vs G2(t-1) r:sHN -- [C](t); wpref(t) w:bufn vs G1(t+1)
// r:bufn -- [F](t); epi2(t) w:sOUT vs flush(t) r:sOUT -- [C](t+1); flush(t-1)
// r:sOUT vs epi2(t) w:sOUT -- [F](t).
__global__ __launch_bounds__(256, 2) void recon_kernel(const float* __restrict__ se,
                                                       const float* __restrict__ rb1,
                                                       const float* __restrict__ rb2,
                                                       const unsigned char* __restrict__ ws,
                                                       float* __restrict__ out3) {
  __shared__ unsigned char smem[59136];

  const int bid = blockIdx.x;
  const int tid = threadIdx.x;
  const int wave = tid >> 6, lane = tid & 63;
  const int lr = lane & 15, lk = lane >> 4;

  unsigned char* sSE0 = smem;                              // 16KB
  unsigned char* sSE1 = smem + 16384;                      // 16KB
  unsigned char* sHN  = smem + 32768;                      // 16KB
  unsigned char* sOUT = smem + 49152;                      // 64 x 72 bf16 = 9216B (padded rows)
  float* sBIAS = reinterpret_cast<float*>(smem + 58368);   // [0..127] rb1, [128..191] rb2

  const int n = bid & 127;   // linear id % 8 == n % 8 -> same-n blocks share XCD
  const int btg = bid >> 7;  // 0..7
  const int b0 = btg * 512;

  const int wm = wave >> 1, wq = wave & 1;  // wm: out-row half, wq: b half (32 each)

  // W1 A-fragments (loop-invariant -> VGPR, 64 regs)
  const unsigned char* w1b = ws + OFF_W1 + (size_t)n * 32768;
  const unsigned char* w2b = ws + OFF_W2 + (size_t)n * 16384;
  bf16x8 w1f[4][4];
#pragma unroll
  for (int m = 0; m < 4; ++m)
#pragma unroll
    for (int kk = 0; kk < 4; ++kk)
      w1f[m][kk] = gfrag_ld(w1b, wm * 64 + m * 16 + lr, kk * 4 + lk);

  // biases -> LDS stub (no VGPR held across phases)
  if (tid < 192)
    sBIAS[tid] = (tid < 128) ? rb1[(size_t)n * 128 + tid] : rb2[(size_t)n * 64 + tid - 128];

  // stage SE subtile 0 directly
  stage_f32_tile(se + ((size_t)b0 * 128 + n) * 128, 128 * 128, sSE0, tid, 64);
  unsigned short* outus = reinterpret_cast<unsigned short*>(out3);

  // per-iter tmp flush: 4 threads per b-row, each moves 32B (2x uint4) ->
  // one full 128B contiguous line per (b,n) row.
  const int fb = tid >> 2, fqt = tid & 3;
  auto flush_out = [&](int tt) {
    uint4 v0 = *reinterpret_cast<const uint4*>(sOUT + fb * 144 + fqt * 32);
    uint4 v1 = *reinterpret_cast<const uint4*>(sOUT + fb * 144 + fqt * 32 + 16);
    unsigned short* dst = outus + (size_t)(b0 + tt * 64 + fb) * 16384 + 8192 + n * 64 + fqt * 16;
    *reinterpret_cast<uint4*>(dst) = v0;
    *reinterpret_cast<uint4*>(dst + 8) = v1;
  };

  float4 fra[4], frb[4];  // next-tile staging registers
  {  // prologue: issue loads for tile 1 (consumed at wpref of t=0)
    const float* sb = se + ((size_t)(b0 + 64) * 128 + n) * 128;
#pragma unroll
    for (int k = 0; k < 4; ++k) {
      int c = tid + k * 256;
      int row = c >> 4, s = c & 15;
      const float* p = sb + (size_t)row * 16384 + s * 8;
      fra[k] = *reinterpret_cast<const float4*>(p);
      frb[k] = *reinterpret_cast<const float4*>(p + 4);
    }
  }
  bar_lds();  // tile 0 + biases staged (no vmcnt drain: tile-1 loads stay in flight)

#pragma unroll 1
  for (int t = 0; t < 8; ++t) {
    unsigned char* bufc = (t & 1) ? sSE1 : sSE0;
    unsigned char* bufn = (t & 1) ? sSE0 : sSE1;

    // GEMM1': 128(h_out) x 64(b) x 128(k); wave owns 64 x 32
    f32x4 acc[4][2] = {};
#pragma unroll
    for (int kk = 0; kk < 4; ++kk) {
      const int slot = kk * 4 + lk;
      bf16x8 bv[2];
#pragma unroll
      for (int q = 0; q < 2; ++q) bv[q] = frag_ld(bufc, wq * 32 + q * 16 + lr, slot);
#pragma unroll
      for (int m = 0; m < 4; ++m)
#pragma unroll
        for (int q = 0; q < 2; ++q)
          acc[m][q] = __builtin_amdgcn_mfma_f32_16x16x32_bf16(w1f[m][kk], bv[q], acc[m][q], 0, 0, 0);
    }
    bar_lds();  // [C] G1 reads of bufc done; prev epi2's sOUT writes visible; prev G2's sHN reads done

    // flush previous tile's output from sOUT (reads sealed from epi2(t) by [F](t))
    if (t > 0) flush_out(t - 1);

    // write prefetched SE(t+1) (frees fra/frb early)
    if (t < 7) {
#pragma unroll
      for (int k = 0; k < 4; ++k) {
        int c = tid + k * 256;
        int row = c >> 4, s = c & 15;
        union { unsigned short u[8]; uint4 v; } pk;
#pragma unroll
        for (int j = 0; j < 4; ++j) pk.u[j] = f2bf(fra[k][j]);
#pragma unroll
        for (int j = 0; j < 4; ++j) pk.u[4 + j] = f2bf(frb[k][j]);
        *reinterpret_cast<uint4*>(bufn + row * 256 + ((s ^ (row & 7)) << 4)) = pk.v;
      }
    }
    // issue loads for tile t+2 (consumed at wpref(t+1); crosses two non-draining barriers)
    if (t < 6) {
      const float* sb = se + ((size_t)(b0 + (t + 2) * 64) * 128 + n) * 128;
#pragma unroll
      for (int k = 0; k < 4; ++k) {
        int c = tid + k * 256;
        int row = c >> 4, s = c & 15;
        const float* p = sb + (size_t)row * 16384 + s * 8;
        fra[k] = *reinterpret_cast<const float4*>(p);
        frb[k] = *reinterpret_cast<const float4*>(p + 4);
      }
    }
    // W2 A-fragments: re-read from L2 each iter (same addr -> hot); used after [F]
    bf16x8 w2f[2][4];
#pragma unroll
    for (int m = 0; m < 2; ++m)
#pragma unroll
      for (int kk = 0; kk < 4; ++kk)
        w2f[m][kk] = gfrag_ld(w2b, wm * 32 + m * 16 + lr, kk * 4 + lk);

    // epilogue1: hn[b][k] = relu(C1t[k][b] + rb1[k]) -> bf16 into sHN (bias from LDS)
#pragma unroll
    for (int m = 0; m < 4; ++m) {
      const int k0 = wm * 64 + m * 16 + lk * 4;
      const int s16 = k0 >> 3, half = (k0 >> 2) & 1;
      union { float4 v; float f[4]; } b1;
      b1.v = *reinterpret_cast<const float4*>(sBIAS + k0);
#pragma unroll
      for (int q = 0; q < 2; ++q) {
        const int b = wq * 32 + q * 16 + lr;
        union { unsigned short u[4]; uint2 v; } pk;
#pragma unroll
        for (int j = 0; j < 4; ++j) {
          float v = acc[m][q][j] + b1.f[j];
          v = v > 0.f ? v : 0.f;
          pk.u[j] = f2bf(v);
        }
        *reinterpret_cast<uint2*>(sHN + b * 256 + ((s16 ^ (b & 7)) << 4) + half * 8) = pk.v;
      }
    }
    bar_lds();  // [F] sHN + bufn ready; flush(t-1) reads sealed before epi2(t)

    // GEMM2': 64(w) x 64(b) x 128(k); wave owns 32 x 32
    f32x4 acc2[2][2] = {};
#pragma unroll
    for (int kk = 0; kk < 4; ++kk) {
      const int slot = kk * 4 + lk;
      bf16x8 bv[2];
#pragma unroll
      for (int q = 0; q < 2; ++q) bv[q] = frag_ld(sHN, wq * 32 + q * 16 + lr, slot);
#pragma unroll
      for (int m = 0; m < 2; ++m)
#pragma unroll
        for (int q = 0; q < 2; ++q)
          acc2[m][q] = __builtin_amdgcn_mfma_f32_16x16x32_bf16(w2f[m][kk], bv[q], acc2[m][q], 0, 0, 0);
    }

    // epilogue2: bf16 into sOUT[b][w] (padded rows 144B)
#pragma unroll
    for (int m = 0; m < 2; ++m) {
      const int w0 = wm * 32 + m * 16 + lk * 4;
      union { float4 v; float f[4]; } b2;
      b2.v = *reinterpret_cast<const float4*>(sBIAS + 128 + w0);
#pragma unroll
      for (int q = 0; q < 2; ++q) {
        const int bloc = wq * 32 + q * 16 + lr;
        union { unsigned short u[4]; uint2 v; } pk;
#pragma unroll
        for (int j = 0; j < 4; ++j) pk.u[j] = f2bf(acc2[m][q][j] + b2.f[j]);
        *reinterpret_cast<uint2*>(sOUT + bloc * 144 + w0 * 2) = pk.v;
      }
    }
    // no closing barrier: epi2(t) w:sOUT vs flush(t) r:sOUT split by [C](t+1).
  }
  bar_lds();       // seal epi2(7)'s sOUT writes
  flush_out(7);    // final tile flush
}

// ================ K3: transpose (4096 blocks) || f2 (192 blocks) ================
__global__ __launch_bounds__(256) void transpose_f2_kernel(float* __restrict__ out3,
                                                           const unsigned char* __restrict__ ws,
                                                           const float* __restrict__ fc2b,
                                                           float* __restrict__ out2) {
  __shared__ unsigned char smem[32768];
  const int bid = blockIdx.x;
  const int tid = threadIdx.x;
  const int wave = tid >> 6, lane = tid & 63;

  if (bid >= 4096) {
    // ---- f2 path: 192 blocks (bt 0..63 x ch 0..2), 64 b-rows each ----
    const int fid = bid - 4096;
    const int bt = fid & 63, ch = fid >> 6;
    const int b0 = bt * 64;
    const int lr = lane & 15, lk = lane >> 4;
    unsigned char* sB = smem;  // 32KB F2s chunk
    {
      const uint4* bp = reinterpret_cast<const uint4*>(ws + OFF_F2 + (size_t)ch * 32768);
      uint4* db = reinterpret_cast<uint4*>(sB);
      for (int c = tid; c < 2048; c += 256) db[c] = bp[c];
    }
    __syncthreads();

    const int wm = wave >> 1, wn = wave & 1;
    const unsigned char* htile = ws + OFF_H + (size_t)bt * 16384;

    f32x4 acc[2][4] = {};
#pragma unroll
    for (int kk = 0; kk < 4; ++kk) {
      const int slot = kk * 4 + lk;
      bf16x8 af[2], bfv[4];
#pragma unroll
      for (int m = 0; m < 2; ++m) af[m] = frag_ld(htile, wm * 32 + m * 16 + lr, slot);
#pragma unroll
      for (int q = 0; q < 4; ++q) bfv[q] = frag_ld(sB, wn * 64 + q * 16 + lr, slot);
#pragma unroll
      for (int m = 0; m < 2; ++m)
#pragma unroll
        for (int q = 0; q < 4; ++q)
          acc[m][q] = __builtin_amdgcn_mfma_f32_16x16x32_bf16(af[m], bfv[q], acc[m][q], 0, 0, 0);
    }

#pragma unroll
    for (int q = 0; q < 4; ++q) {
      int o = ch * 128 + wn * 64 + q * 16 + lr;
      float bias = fc2b[o];
#pragma unroll
      for (int m = 0; m < 2; ++m) {
#pragma unroll
        for (int j = 0; j < 4; ++j) {
          int r = wm * 32 + m * 16 + lk * 4 + j;
          out2[(size_t)(b0 + r) * 384 + o] = acc[m][q][j] + bias;
        }
      }
    }
    return;
  }

  // ---- transpose path: tmp bf16 [b][n][w] -> out3 fp32 [b][w][n], LDS-free ----
  const int b = bid;
  const unsigned short* t = reinterpret_cast<const unsigned short*>(out3) + (size_t)b * 16384 + 8192;
  float* dst = out3 + (size_t)b * 8192;
  uint4 r[2][2];
#pragma unroll
  for (int half = 0; half < 2; ++half) {
    const int g = half * 4 + wave;
    r[half][0] = *reinterpret_cast<const uint4*>(t + lane * 64 + g * 8);
    r[half][1] = *reinterpret_cast<const uint4*>(t + (size_t)(lane + 64) * 64 + g * 8);
  }
  __syncthreads();  // all reads done before dst writes clobber the tmp region
#pragma unroll
  for (int half = 0; half < 2; ++half) {
    const int g = half * 4 + wave;
    union { uint4 v; unsigned short u[8]; } p0, p1;
    p0.v = r[half][0];
    p1.v = r[half][1];
#pragma unroll
    for (int j = 0; j < 8; ++j) {
      dst[(g * 8 + j) * 128 + lane] = bf2f(p0.u[j]);
      dst[(g * 8 + j) * 128 + lane + 64] = bf2f(p1.u[j]);
    }
  }
}

extern "C" void kernel_launch(void* const* d_in, const int* in_sizes, int n_in,
                              void* d_out, int out_size, void* d_ws, size_t ws_size,
                              hipStream_t stream) {
  const float* emb  = (const float*)d_in[0];
  const float* se   = (const float*)d_in[1];
  const float* slog = (const float*)d_in[2];
  const float* fc1w = (const float*)d_in[3];
  const float* fc1b = (const float*)d_in[4];
  const float* fc2w = (const float*)d_in[5];
  const float* fc2b = (const float*)d_in[6];
  const float* rw1  = (const float*)d_in[7];
  const float* rb1  = (const float*)d_in[8];
  const float* rw2  = (const float*)d_in[9];
  const float* rb2  = (const float*)d_in[10];
  float* out = (float*)d_out;
  unsigned char* ws = (unsigned char*)d_ws;

  float* out2 = out + (size_t)B_SZ * N_SZ;
  float* out3 = out2 + (size_t)B_SZ * 384;

  // K1: weight prep + logits copy || forecast stage 1
  prep_f1_kernel<<<2136, 256, 0, stream>>>(rw1, rw2, fc2w, slog, emb, fc1w, fc1b, out, ws);

  // K2: reconstruction only -- exactly 2.0 occupancy rounds (1024 blocks, 2/CU)
  recon_kernel<<<1024, 256, 0, stream>>>(se, rb1, rb2, ws, out3);

  // K3: transpose to final [b][w][n] fp32 || forecast stage 2
  transpose_f2_kernel<<<4288, 256, 0, stream>>>(out3, ws, fc2b, out2);
}

// Round 16
// 130.518 us; speedup vs baseline: 1.0544x; 1.0475x over previous
//
#include <hip/hip_runtime.h>
#include <hip/hip_bf16.h>
#include <stdint.h>

typedef __attribute__((ext_vector_type(8))) short bf16x8;
typedef __attribute__((ext_vector_type(4))) float f32x4;

#define DEVI static __device__ __forceinline__

// Problem sizes (fixed)
static constexpr int B_SZ = 4096, N_SZ = 128, H_SZ = 128, W_SZ = 64;

// ws layout (bytes), all 16B aligned
static constexpr size_t OFF_W1 = 0;                      // 128 * 128*128 bf16 = 4 MB (UNswizzled [n][c][h])
static constexpr size_t OFF_W2 = OFF_W1 + 4194304;       // 128 * 64*128 bf16 = 2 MB (UNswizzled [n][w][k])
static constexpr size_t OFF_F1 = OFF_W2 + 2097152;       // (unused)
static constexpr size_t OFF_F2 = OFF_F1 + 32768;         // 384*128 bf16 = 96 KB (swizzled [o][j])
static constexpr size_t OFF_H  = OFF_F2 + 98304;         // 64 tiles x 16KB bf16 (swizzled 64-row h tiles)

DEVI unsigned short f2bf(float f) {
  union { __hip_bfloat16 b; unsigned short u; } cv;
  cv.b = __float2bfloat16(f);
  return cv.u;
}
DEVI float bf2f(unsigned short u) {
  union { unsigned int i; float f; } cv;
  cv.i = ((unsigned int)u) << 16;
  return cv.f;
}

// Raw workgroup barrier: execution sync + LDS visibility (lgkmcnt), but does NOT
// drain vmcnt -> global prefetch loads stay in flight across it.
DEVI void bar_lds() {
  __builtin_amdgcn_sched_barrier(0);
  asm volatile("s_waitcnt lgkmcnt(0)" ::: "memory");
  __builtin_amdgcn_s_barrier();
  __builtin_amdgcn_sched_barrier(0);
}

// Read one MFMA fragment (8 contiguous bf16 along k) from a swizzled tile
// (LDS or global). Row stride 256B; 16B slot s stored at (s ^ (row&7)).
DEVI bf16x8 frag_ld(const unsigned char* base, int row, int kslot) {
  return *reinterpret_cast<const bf16x8*>(base + row * 256 + (((kslot ^ (row & 7)) << 4)));
}
// Unswizzled fragment read (global memory, 256B rows).
DEVI bf16x8 gfrag_ld(const unsigned char* base, int row, int kslot) {
  return *reinterpret_cast<const bf16x8*>(base + row * 256 + (kslot << 4));
}

// Stage an nrows x 128 fp32 tile (row stride in elems) into swizzled bf16 LDS.
template <int NT>
DEVI void stage_f32_tile(const float* src, int row_stride, unsigned char* dst, int tid, int nrows) {
  for (int t = tid; t < nrows * 16; t += NT) {
    int row = t >> 4, s = t & 15;
    const float* p = src + (size_t)row * row_stride + s * 8;
    union { unsigned short u[8]; uint4 v; } pk;
#pragma unroll
    for (int j = 0; j < 8; ++j) pk.u[j] = f2bf(p[j]);
    *reinterpret_cast<uint4*>(dst + row * 256 + ((s ^ (row & 7)) << 4)) = pk.v;
  }
}

// ================ K1: prep (W1,W2,F2s,logits) || f1 (h = relu(emb@fc1^T+b1)) ================
__global__ __launch_bounds__(256) void prep_f1_kernel(const float* __restrict__ rw1,
                                                      const float* __restrict__ rw2,
                                                      const float* __restrict__ fc2w,
                                                      const float* __restrict__ slog,
                                                      const float* __restrict__ emb,
                                                      const float* __restrict__ fc1w,
                                                      const float* __restrict__ fc1b,
                                                      float* __restrict__ out,
                                                      unsigned char* __restrict__ ws) {
  __shared__ unsigned char sA[16384];  // f1: emb 64-row tile
  __shared__ unsigned char sB[32768];  // f1: fc1w tile

  const int bid = blockIdx.x;
  const int tid = threadIdx.x;
  if (bid < 2072) {
    const int T_W1 = 128 * 128 * 16;  // (n,s,c): W1t[n][c][h=s*8+j] = rw1[n][h][c]
    const int T_W2 = 128 * 64 * 16;   // (n,s,w): W2t[n][w][k=s*8+j] = rw2[n][k][w]
    const int T_F2 = 384 * 16;        // (o,s):   F2s[o][j] = fc2w[o][j]  (swizzled)
    int id = bid * 256 + tid;
    if (id < T_W1) {
      int c = id & 127, rest = id >> 7;
      int s = rest & 15, n = rest >> 4;
      const float* src = rw1 + (size_t)n * 16384 + (size_t)(s * 8) * 128 + c;
      union { unsigned short u[8]; uint4 v; } pk;
#pragma unroll
      for (int j = 0; j < 8; ++j) pk.u[j] = f2bf(src[(size_t)j * 128]);
      size_t dst = OFF_W1 + ((size_t)n * 128 + c) * 256 + (size_t)(s << 4);
      *reinterpret_cast<uint4*>(ws + dst) = pk.v;
      return;
    }
    id -= T_W1;
    if (id < T_W2) {
      int w = id & 63, rest = id >> 6;
      int s = rest & 15, n = rest >> 4;
      const float* src = rw2 + (size_t)n * 8192 + (size_t)(s * 8) * 64 + w;
      union { unsigned short u[8]; uint4 v; } pk;
#pragma unroll
      for (int j = 0; j < 8; ++j) pk.u[j] = f2bf(src[(size_t)j * 64]);
      size_t dst = OFF_W2 + ((size_t)n * 64 + w) * 256 + (size_t)(s << 4);
      *reinterpret_cast<uint4*>(ws + dst) = pk.v;
      return;
    }
    id -= T_W2;
    if (id < T_F2) {
      int s = id & 15, o = id >> 4;
      const float* src = fc2w + (size_t)o * 128 + s * 8;
      union { unsigned short u[8]; uint4 v; } pk;
#pragma unroll
      for (int j = 0; j < 8; ++j) pk.u[j] = f2bf(src[j]);
      *reinterpret_cast<uint4*>(ws + OFF_F2 + (size_t)o * 256 + ((s ^ (o & 7)) << 4)) = pk.v;
      return;
    }
    id -= T_F2;
    // logits passthrough: 2MB as uint4
    reinterpret_cast<uint4*>(out)[id] = reinterpret_cast<const uint4*>(slog)[id];
    return;
  }

  // ---- f1 path: 64 blocks x 64 b-rows ----
  const int bt = bid - 2072;
  const int b0 = bt * 64;
  stage_f32_tile<256>(fc1w, 128, sB, tid, 128);
  stage_f32_tile<256>(emb + (size_t)b0 * 128, 128, sA, tid, 64);
  __syncthreads();

  const int wave = tid >> 6, lane = tid & 63;
  const int wm = wave >> 1, wn = wave & 1;
  const int lr = lane & 15, lk = lane >> 4;

  f32x4 acc[2][4] = {};
#pragma unroll
  for (int kk = 0; kk < 4; ++kk) {
    const int slot = kk * 4 + lk;
    bf16x8 af[2], bfv[4];
#pragma unroll
    for (int m = 0; m < 2; ++m) af[m] = frag_ld(sA, wm * 32 + m * 16 + lr, slot);
#pragma unroll
    for (int q = 0; q < 4; ++q) bfv[q] = frag_ld(sB, wn * 64 + q * 16 + lr, slot);
#pragma unroll
    for (int m = 0; m < 2; ++m)
#pragma unroll
      for (int q = 0; q < 4; ++q)
        acc[m][q] = __builtin_amdgcn_mfma_f32_16x16x32_bf16(af[m], bfv[q], acc[m][q], 0, 0, 0);
  }

  unsigned char* tile = ws + OFF_H + (size_t)bt * 16384;
#pragma unroll
  for (int q = 0; q < 4; ++q) {
    int c = wn * 64 + q * 16 + lr;
    float bias = fc1b[c];
#pragma unroll
    for (int m = 0; m < 2; ++m) {
#pragma unroll
      for (int j = 0; j < 4; ++j) {
        int r = wm * 32 + m * 16 + lk * 4 + j;
        float v = acc[m][q][j] + bias;
        v = v > 0.f ? v : 0.f;
        *reinterpret_cast<unsigned short*>(tile + r * 256 + ((c * 2) ^ ((r & 7) << 4))) = f2bf(v);
      }
    }
  }
}

// ================ K2: recon, 512-thread blocks (8 waves) for 2x waves/CU ================
// Same v13 pipeline, work split over 8 waves: G1 wave = 32 h_out x 32 b (wm 0..3,
// wq 0..1); G2 wave = 16 w x 32 b. Per-thread registers ~halve (w1f 32, w2f 16,
// acc 16+8, staging 16) -> target <=128 VGPR so HW runs 2 blocks/CU = 16 waves/CU
// (4/SIMD, double v13's TLP). NO forced min-waves (v6/v10 lesson).
// Hazards identical to v13: epi1(t) w:sHN vs G2(t-1) r:sHN -- [C](t); wpref(t)
// w:bufn vs G1(t+1) r:bufn -- [F](t); epi2(t) w:sOUT vs flush(t) r:sOUT --
// [C](t+1); flush(t-1) r:sOUT vs epi2(t) w:sOUT -- [F](t).
__global__ __launch_bounds__(512) void recon_kernel(const float* __restrict__ se,
                                                    const float* __restrict__ rb1,
                                                    const float* __restrict__ rb2,
                                                    const unsigned char* __restrict__ ws,
                                                    float* __restrict__ out3) {
  __shared__ unsigned char smem[59136];

  const int bid = blockIdx.x;
  const int tid = threadIdx.x;
  const int wave = tid >> 6, lane = tid & 63;
  const int lr = lane & 15, lk = lane >> 4;

  unsigned char* sSE0 = smem;                              // 16KB
  unsigned char* sSE1 = smem + 16384;                      // 16KB
  unsigned char* sHN  = smem + 32768;                      // 16KB
  unsigned char* sOUT = smem + 49152;                      // 64 x 72 bf16 = 9216B (padded rows)
  float* sBIAS = reinterpret_cast<float*>(smem + 58368);   // [0..127] rb1, [128..191] rb2

  const int n = bid & 127;   // linear id % 8 == n % 8 -> same-n blocks share XCD
  const int btg = bid >> 7;  // 0..7
  const int b0 = btg * 512;

  const int wm = wave >> 1;  // 0..3: G1 h_out 32-row group / G2 w 16-row group
  const int wq = wave & 1;   // 0..1: b half (32 each)

  // W1 A-fragments (loop-invariant -> VGPR, 32 regs: 2 x 16 rows this wave)
  const unsigned char* w1b = ws + OFF_W1 + (size_t)n * 32768;
  const unsigned char* w2b = ws + OFF_W2 + (size_t)n * 16384;
  bf16x8 w1f[2][4];
#pragma unroll
  for (int m = 0; m < 2; ++m)
#pragma unroll
    for (int kk = 0; kk < 4; ++kk)
      w1f[m][kk] = gfrag_ld(w1b, wm * 32 + m * 16 + lr, kk * 4 + lk);

  // biases -> LDS stub
  if (tid < 192)
    sBIAS[tid] = (tid < 128) ? rb1[(size_t)n * 128 + tid] : rb2[(size_t)n * 64 + tid - 128];

  // stage SE subtile 0 directly
  stage_f32_tile<512>(se + ((size_t)b0 * 128 + n) * 128, 128 * 128, sSE0, tid, 64);
  unsigned short* outus = reinterpret_cast<unsigned short*>(out3);

  // per-iter tmp flush: 8 threads per b-row, 16B each -> full 128B contiguous line.
  const int fb = tid >> 3, fqt = tid & 7;
  auto flush_out = [&](int tt) {
    uint4 v0 = *reinterpret_cast<const uint4*>(sOUT + fb * 144 + fqt * 16);
    unsigned short* dst = outus + (size_t)(b0 + tt * 64 + fb) * 16384 + 8192 + n * 64 + fqt * 8;
    *reinterpret_cast<uint4*>(dst) = v0;
  };

  float4 fra[2], frb[2];  // next-tile staging registers (2 chunks x 32B, 512 threads)
  {  // prologue: issue loads for tile 1 (consumed at wpref of t=0)
    const float* sb = se + ((size_t)(b0 + 64) * 128 + n) * 128;
#pragma unroll
    for (int k = 0; k < 2; ++k) {
      int c = tid + k * 512;
      int row = c >> 4, s = c & 15;
      const float* p = sb + (size_t)row * 16384 + s * 8;
      fra[k] = *reinterpret_cast<const float4*>(p);
      frb[k] = *reinterpret_cast<const float4*>(p + 4);
    }
  }
  bar_lds();  // tile 0 + biases staged (no vmcnt drain: tile-1 loads stay in flight)

#pragma unroll 1
  for (int t = 0; t < 8; ++t) {
    unsigned char* bufc = (t & 1) ? sSE1 : sSE0;
    unsigned char* bufn = (t & 1) ? sSE0 : sSE1;

    // GEMM1': 128(h_out) x 64(b) x 128(k); wave owns 32 x 32
    f32x4 acc[2][2] = {};
#pragma unroll
    for (int kk = 0; kk < 4; ++kk) {
      const int slot = kk * 4 + lk;
      bf16x8 bv[2];
#pragma unroll
      for (int q = 0; q < 2; ++q) bv[q] = frag_ld(bufc, wq * 32 + q * 16 + lr, slot);
#pragma unroll
      for (int m = 0; m < 2; ++m)
#pragma unroll
        for (int q = 0; q < 2; ++q)
          acc[m][q] = __builtin_amdgcn_mfma_f32_16x16x32_bf16(w1f[m][kk], bv[q], acc[m][q], 0, 0, 0);
    }
    bar_lds();  // [C] G1 reads of bufc done; prev epi2's sOUT writes visible; prev G2's sHN reads done

    // flush previous tile's output from sOUT (reads sealed from epi2(t) by [F](t))
    if (t > 0) flush_out(t - 1);

    // write prefetched SE(t+1) (frees fra/frb early)
    if (t < 7) {
#pragma unroll
      for (int k = 0; k < 2; ++k) {
        int c = tid + k * 512;
        int row = c >> 4, s = c & 15;
        union { unsigned short u[8]; uint4 v; } pk;
#pragma unroll
        for (int j = 0; j < 4; ++j) pk.u[j] = f2bf(fra[k][j]);
#pragma unroll
        for (int j = 0; j < 4; ++j) pk.u[4 + j] = f2bf(frb[k][j]);
        *reinterpret_cast<uint4*>(bufn + row * 256 + ((s ^ (row & 7)) << 4)) = pk.v;
      }
    }
    // issue loads for tile t+2 (consumed at wpref(t+1); crosses two non-draining barriers)
    if (t < 6) {
      const float* sb = se + ((size_t)(b0 + (t + 2) * 64) * 128 + n) * 128;
#pragma unroll
      for (int k = 0; k < 2; ++k) {
        int c = tid + k * 512;
        int row = c >> 4, s = c & 15;
        const float* p = sb + (size_t)row * 16384 + s * 8;
        fra[k] = *reinterpret_cast<const float4*>(p);
        frb[k] = *reinterpret_cast<const float4*>(p + 4);
      }
    }
    // W2 A-fragments: re-read from L2 each iter (same addr -> hot); used after [F]
    bf16x8 w2f[4];
#pragma unroll
    for (int kk = 0; kk < 4; ++kk)
      w2f[kk] = gfrag_ld(w2b, wm * 16 + lr, kk * 4 + lk);

    // epilogue1: hn[b][k] = relu(C1t[k][b] + rb1[k]) -> bf16 into sHN (bias from LDS)
    // lane: b = wq*32+q*16+lr, k = wm*32+m*16+lk*4+j
#pragma unroll
    for (int m = 0; m < 2; ++m) {
      const int k0 = wm * 32 + m * 16 + lk * 4;
      const int s16 = k0 >> 3, half = (k0 >> 2) & 1;
      union { float4 v; float f[4]; } b1;
      b1.v = *reinterpret_cast<const float4*>(sBIAS + k0);
#pragma unroll
      for (int q = 0; q < 2; ++q) {
        const int b = wq * 32 + q * 16 + lr;
        union { unsigned short u[4]; uint2 v; } pk;
#pragma unroll
        for (int j = 0; j < 4; ++j) {
          float v = acc[m][q][j] + b1.f[j];
          v = v > 0.f ? v : 0.f;
          pk.u[j] = f2bf(v);
        }
        *reinterpret_cast<uint2*>(sHN + b * 256 + ((s16 ^ (b & 7)) << 4) + half * 8) = pk.v;
      }
    }
    bar_lds();  // [F] sHN + bufn ready; flush(t-1) reads sealed before epi2(t)

    // GEMM2': 64(w) x 64(b) x 128(k); wave owns 16 x 32
    f32x4 acc2[2] = {};
#pragma unroll
    for (int kk = 0; kk < 4; ++kk) {
      const int slot = kk * 4 + lk;
      bf16x8 bv[2];
#pragma unroll
      for (int q = 0; q < 2; ++q) bv[q] = frag_ld(sHN, wq * 32 + q * 16 + lr, slot);
#pragma unroll
      for (int q = 0; q < 2; ++q)
        acc2[q] = __builtin_amdgcn_mfma_f32_16x16x32_bf16(w2f[kk], bv[q], acc2[q], 0, 0, 0);
    }

    // epilogue2: bf16 into sOUT[b][w] (padded rows 144B); w = wm*16+lk*4+j
    {
      const int w0 = wm * 16 + lk * 4;
      union { float4 v; float f[4]; } b2;
      b2.v = *reinterpret_cast<const float4*>(sBIAS + 128 + w0);
#pragma unroll
      for (int q = 0; q < 2; ++q) {
        const int bloc = wq * 32 + q * 16 + lr;
        union { unsigned short u[4]; uint2 v; } pk;
#pragma unroll
        for (int j = 0; j < 4; ++j) pk.u[j] = f2bf(acc2[q][j] + b2.f[j]);
        *reinterpret_cast<uint2*>(sOUT + bloc * 144 + w0 * 2) = pk.v;
      }
    }
    // no closing barrier: epi2(t) w:sOUT vs flush(t) r:sOUT split by [C](t+1).
  }
  bar_lds();       // seal epi2(7)'s sOUT writes
  flush_out(7);    // final tile flush
}

// ================ K3: transpose (4096 blocks) || f2 (192 blocks) ================
__global__ __launch_bounds__(256) void transpose_f2_kernel(float* __restrict__ out3,
                                                           const unsigned char* __restrict__ ws,
                                                           const float* __restrict__ fc2b,
                                                           float* __restrict__ out2) {
  __shared__ unsigned char smem[32768];
  const int bid = blockIdx.x;
  const int tid = threadIdx.x;
  const int wave = tid >> 6, lane = tid & 63;

  if (bid >= 4096) {
    // ---- f2 path: 192 blocks (bt 0..63 x ch 0..2), 64 b-rows each ----
    const int fid = bid - 4096;
    const int bt = fid & 63, ch = fid >> 6;
    const int b0 = bt * 64;
    const int lr = lane & 15, lk = lane >> 4;
    unsigned char* sB = smem;  // 32KB F2s chunk
    {
      const uint4* bp = reinterpret_cast<const uint4*>(ws + OFF_F2 + (size_t)ch * 32768);
      uint4* db = reinterpret_cast<uint4*>(sB);
      for (int c = tid; c < 2048; c += 256) db[c] = bp[c];
    }
    __syncthreads();

    const int wm = wave >> 1, wn = wave & 1;
    const unsigned char* htile = ws + OFF_H + (size_t)bt * 16384;

    f32x4 acc[2][4] = {};
#pragma unroll
    for (int kk = 0; kk < 4; ++kk) {
      const int slot = kk * 4 + lk;
      bf16x8 af[2], bfv[4];
#pragma unroll
      for (int m = 0; m < 2; ++m) af[m] = frag_ld(htile, wm * 32 + m * 16 + lr, slot);
#pragma unroll
      for (int q = 0; q < 4; ++q) bfv[q] = frag_ld(sB, wn * 64 + q * 16 + lr, slot);
#pragma unroll
      for (int m = 0; m < 2; ++m)
#pragma unroll
        for (int q = 0; q < 4; ++q)
          acc[m][q] = __builtin_amdgcn_mfma_f32_16x16x32_bf16(af[m], bfv[q], acc[m][q], 0, 0, 0);
    }

#pragma unroll
    for (int q = 0; q < 4; ++q) {
      int o = ch * 128 + wn * 64 + q * 16 + lr;
      float bias = fc2b[o];
#pragma unroll
      for (int m = 0; m < 2; ++m) {
#pragma unroll
        for (int j = 0; j < 4; ++j) {
          int r = wm * 32 + m * 16 + lk * 4 + j;
          out2[(size_t)(b0 + r) * 384 + o] = acc[m][q][j] + bias;
        }
      }
    }
    return;
  }

  // ---- transpose path: tmp bf16 [b][n][w] -> out3 fp32 [b][w][n], LDS-free ----
  const int b = bid;
  const unsigned short* t = reinterpret_cast<const unsigned short*>(out3) + (size_t)b * 16384 + 8192;
  float* dst = out3 + (size_t)b * 8192;
  uint4 r[2][2];
#pragma unroll
  for (int half = 0; half < 2; ++half) {
    const int g = half * 4 + wave;
    r[half][0] = *reinterpret_cast<const uint4*>(t + lane * 64 + g * 8);
    r[half][1] = *reinterpret_cast<const uint4*>(t + (size_t)(lane + 64) * 64 + g * 8);
  }
  __syncthreads();  // all reads done before dst writes clobber the tmp region
#pragma unroll
  for (int half = 0; half < 2; ++half) {
    const int g = half * 4 + wave;
    union { uint4 v; unsigned short u[8]; } p0, p1;
    p0.v = r[half][0];
    p1.v = r[half][1];
#pragma unroll
    for (int j = 0; j < 8; ++j) {
      dst[(g * 8 + j) * 128 + lane] = bf2f(p0.u[j]);
      dst[(g * 8 + j) * 128 + lane + 64] = bf2f(p1.u[j]);
    }
  }
}

extern "C" void kernel_launch(void* const* d_in, const int* in_sizes, int n_in,
                              void* d_out, int out_size, void* d_ws, size_t ws_size,
                              hipStream_t stream) {
  const float* emb  = (const float*)d_in[0];
  const float* se   = (const float*)d_in[1];
  const float* slog = (const float*)d_in[2];
  const float* fc1w = (const float*)d_in[3];
  const float* fc1b = (const float*)d_in[4];
  const float* fc2w = (const float*)d_in[5];
  const float* fc2b = (const float*)d_in[6];
  const float* rw1  = (const float*)d_in[7];
  const float* rb1  = (const float*)d_in[8];
  const float* rw2  = (const float*)d_in[9];
  const float* rb2  = (const float*)d_in[10];
  float* out = (float*)d_out;
  unsigned char* ws = (unsigned char*)d_ws;

  float* out2 = out + (size_t)B_SZ * N_SZ;
  float* out3 = out2 + (size_t)B_SZ * 384;

  // K1: weight prep + logits copy || forecast stage 1
  prep_f1_kernel<<<2136, 256, 0, stream>>>(rw1, rw2, fc2w, slog, emb, fc1w, fc1b, out, ws);

  // K2: reconstruction, 512-thread blocks (target 2 blocks/CU = 16 waves/CU)
  recon_kernel<<<1024, 512, 0, stream>>>(se, rb1, rb2, ws, out3);

  // K3: transpose to final [b][w][n] fp32 || forecast stage 2
  transpose_f2_kernel<<<4288, 256, 0, stream>>>(out3, ws, fc2b, out2);
}

// Round 17
// 130.483 us; speedup vs baseline: 1.0546x; 1.0003x over previous
//
#include <hip/hip_runtime.h>
#include <hip/hip_bf16.h>
#include <stdint.h>

typedef __attribute__((ext_vector_type(8))) short bf16x8;
typedef __attribute__((ext_vector_type(4))) float f32x4;

#define DEVI static __device__ __forceinline__

// Problem sizes (fixed)
static constexpr int B_SZ = 4096, N_SZ = 128, H_SZ = 128, W_SZ = 64;

// ws layout (bytes), all 16B aligned
static constexpr size_t OFF_W1 = 0;                      // 128 * 128*128 bf16 = 4 MB (UNswizzled [n][c][h])
static constexpr size_t OFF_W2 = OFF_W1 + 4194304;       // 128 * 64*128 bf16 = 2 MB (UNswizzled [n][w][k])
static constexpr size_t OFF_F1 = OFF_W2 + 2097152;       // (unused)
static constexpr size_t OFF_F2 = OFF_F1 + 32768;         // 384*128 bf16 = 96 KB (swizzled [o][j])
static constexpr size_t OFF_H  = OFF_F2 + 98304;         // 64 tiles x 16KB bf16 (swizzled 64-row h tiles)

DEVI unsigned short f2bf(float f) {
  union { __hip_bfloat16 b; unsigned short u; } cv;
  cv.b = __float2bfloat16(f);
  return cv.u;
}
DEVI float bf2f(unsigned short u) {
  union { unsigned int i; float f; } cv;
  cv.i = ((unsigned int)u) << 16;
  return cv.f;
}

// Raw workgroup barrier: execution sync + LDS visibility (lgkmcnt), but does NOT
// drain vmcnt -> global prefetch loads stay in flight across it.
DEVI void bar_lds() {
  __builtin_amdgcn_sched_barrier(0);
  asm volatile("s_waitcnt lgkmcnt(0)" ::: "memory");
  __builtin_amdgcn_s_barrier();
  __builtin_amdgcn_sched_barrier(0);
}

// Read one MFMA fragment (8 contiguous bf16 along k) from a swizzled tile
// (LDS or global). Row stride 256B; 16B slot s stored at (s ^ (row&7)).
DEVI bf16x8 frag_ld(const unsigned char* base, int row, int kslot) {
  return *reinterpret_cast<const bf16x8*>(base + row * 256 + (((kslot ^ (row & 7)) << 4)));
}
// Unswizzled fragment read (global memory, 256B rows).
DEVI bf16x8 gfrag_ld(const unsigned char* base, int row, int kslot) {
  return *reinterpret_cast<const bf16x8*>(base + row * 256 + (kslot << 4));
}

// Stage an nrows x 128 fp32 tile (row stride in elems) into swizzled bf16 LDS.
template <int NT>
DEVI void stage_f32_tile(const float* src, int row_stride, unsigned char* dst, int tid, int nrows) {
  for (int t = tid; t < nrows * 16; t += NT) {
    int row = t >> 4, s = t & 15;
    const float* p = src + (size_t)row * row_stride + s * 8;
    union { unsigned short u[8]; uint4 v; } pk;
#pragma unroll
    for (int j = 0; j < 8; ++j) pk.u[j] = f2bf(p[j]);
    *reinterpret_cast<uint4*>(dst + row * 256 + ((s ^ (row & 7)) << 4)) = pk.v;
  }
}

// ================ K1: prep (W1,W2,F2s,logits) || f1 (h = relu(emb@fc1^T+b1)) ================
__global__ __launch_bounds__(256) void prep_f1_kernel(const float* __restrict__ rw1,
                                                      const float* __restrict__ rw2,
                                                      const float* __restrict__ fc2w,
                                                      const float* __restrict__ slog,
                                                      const float* __restrict__ emb,
                                                      const float* __restrict__ fc1w,
                                                      const float* __restrict__ fc1b,
                                                      float* __restrict__ out,
                                                      unsigned char* __restrict__ ws) {
  __shared__ unsigned char sA[16384];  // f1: emb 64-row tile
  __shared__ unsigned char sB[32768];  // f1: fc1w tile

  const int bid = blockIdx.x;
  const int tid = threadIdx.x;
  if (bid < 2072) {
    const int T_W1 = 128 * 128 * 16;  // (n,s,c): W1t[n][c][h=s*8+j] = rw1[n][h][c]
    const int T_W2 = 128 * 64 * 16;   // (n,s,w): W2t[n][w][k=s*8+j] = rw2[n][k][w]
    const int T_F2 = 384 * 16;        // (o,s):   F2s[o][j] = fc2w[o][j]  (swizzled)
    int id = bid * 256 + tid;
    if (id < T_W1) {
      int c = id & 127, rest = id >> 7;
      int s = rest & 15, n = rest >> 4;
      const float* src = rw1 + (size_t)n * 16384 + (size_t)(s * 8) * 128 + c;
      union { unsigned short u[8]; uint4 v; } pk;
#pragma unroll
      for (int j = 0; j < 8; ++j) pk.u[j] = f2bf(src[(size_t)j * 128]);
      size_t dst = OFF_W1 + ((size_t)n * 128 + c) * 256 + (size_t)(s << 4);
      *reinterpret_cast<uint4*>(ws + dst) = pk.v;
      return;
    }
    id -= T_W1;
    if (id < T_W2) {
      int w = id & 63, rest = id >> 6;
      int s = rest & 15, n = rest >> 4;
      const float* src = rw2 + (size_t)n * 8192 + (size_t)(s * 8) * 64 + w;
      union { unsigned short u[8]; uint4 v; } pk;
#pragma unroll
      for (int j = 0; j < 8; ++j) pk.u[j] = f2bf(src[(size_t)j * 64]);
      size_t dst = OFF_W2 + ((size_t)n * 64 + w) * 256 + (size_t)(s << 4);
      *reinterpret_cast<uint4*>(ws + dst) = pk.v;
      return;
    }
    id -= T_W2;
    if (id < T_F2) {
      int s = id & 15, o = id >> 4;
      const float* src = fc2w + (size_t)o * 128 + s * 8;
      union { unsigned short u[8]; uint4 v; } pk;
#pragma unroll
      for (int j = 0; j < 8; ++j) pk.u[j] = f2bf(src[j]);
      *reinterpret_cast<uint4*>(ws + OFF_F2 + (size_t)o * 256 + ((s ^ (o & 7)) << 4)) = pk.v;
      return;
    }
    id -= T_F2;
    // logits passthrough: 2MB as uint4
    reinterpret_cast<uint4*>(out)[id] = reinterpret_cast<const uint4*>(slog)[id];
    return;
  }

  // ---- f1 path: 64 blocks x 64 b-rows ----
  const int bt = bid - 2072;
  const int b0 = bt * 64;
  stage_f32_tile<256>(fc1w, 128, sB, tid, 128);
  stage_f32_tile<256>(emb + (size_t)b0 * 128, 128, sA, tid, 64);
  __syncthreads();

  const int wave = tid >> 6, lane = tid & 63;
  const int wm = wave >> 1, wn = wave & 1;
  const int lr = lane & 15, lk = lane >> 4;

  f32x4 acc[2][4] = {};
#pragma unroll
  for (int kk = 0; kk < 4; ++kk) {
    const int slot = kk * 4 + lk;
    bf16x8 af[2], bfv[4];
#pragma unroll
    for (int m = 0; m < 2; ++m) af[m] = frag_ld(sA, wm * 32 + m * 16 + lr, slot);
#pragma unroll
    for (int q = 0; q < 4; ++q) bfv[q] = frag_ld(sB, wn * 64 + q * 16 + lr, slot);
#pragma unroll
    for (int m = 0; m < 2; ++m)
#pragma unroll
      for (int q = 0; q < 4; ++q)
        acc[m][q] = __builtin_amdgcn_mfma_f32_16x16x32_bf16(af[m], bfv[q], acc[m][q], 0, 0, 0);
  }

  unsigned char* tile = ws + OFF_H + (size_t)bt * 16384;
#pragma unroll
  for (int q = 0; q < 4; ++q) {
    int c = wn * 64 + q * 16 + lr;
    float bias = fc1b[c];
#pragma unroll
    for (int m = 0; m < 2; ++m) {
#pragma unroll
      for (int j = 0; j < 4; ++j) {
        int r = wm * 32 + m * 16 + lk * 4 + j;
        float v = acc[m][q][j] + bias;
        v = v > 0.f ? v : 0.f;
        *reinterpret_cast<unsigned short*>(tile + r * 256 + ((c * 2) ^ ((r & 7) << 4))) = f2bf(v);
      }
    }
  }
}

// ================ K2: recon, 512-thread blocks, sHN merged into bufc (LDS 42.75KB) ================
// v16 pipeline with v10's proven in-place hn: epi1 overwrites the consumed SE in
// bufc (same row/swizzle scheme); G2 reads hn from bufc. LDS 59.1 -> 42.75KB so
// 3 blocks/CU are allowed by LDS; if VGPR lands <=~85 the HW runs 24 waves/CU.
// NO forced min-waves (v6/v10 lesson).
// Hazards (2 non-draining barriers/iter):
//   epi1(t) w:bufc  vs G1(t) r:bufc        -- split by [C](t)
//   G2(t)  r:bufc   vs wpref(t+1) w:bufc   -- split by [C](t+1)
//   wpref(t) w:bufn vs G1(t+1) r:bufn      -- split by [F](t)
//   epi2(t) w:sOUT  vs flush(t) r:sOUT     -- split by [C](t+1)
//   flush(t-1) r:sOUT vs epi2(t) w:sOUT    -- split by [F](t)
__global__ __launch_bounds__(512) void recon_kernel(const float* __restrict__ se,
                                                    const float* __restrict__ rb1,
                                                    const float* __restrict__ rb2,
                                                    const unsigned char* __restrict__ ws,
                                                    float* __restrict__ out3) {
  __shared__ unsigned char smem[43520];

  const int bid = blockIdx.x;
  const int tid = threadIdx.x;
  const int wave = tid >> 6, lane = tid & 63;
  const int lr = lane & 15, lk = lane >> 4;

  unsigned char* sSE0 = smem;                              // 16KB (SE, then hn in place)
  unsigned char* sSE1 = smem + 16384;                      // 16KB
  unsigned char* sOUT = smem + 32768;                      // 64 x 72 bf16 = 9216B (padded rows)
  float* sBIAS = reinterpret_cast<float*>(smem + 41984);   // [0..127] rb1, [128..191] rb2

  const int n = bid & 127;   // linear id % 8 == n % 8 -> same-n blocks share XCD
  const int btg = bid >> 7;  // 0..7
  const int b0 = btg * 512;

  const int wm = wave >> 1;  // 0..3: G1 h_out 32-row group / G2 w 16-row group
  const int wq = wave & 1;   // 0..1: b half (32 each)

  // W1 A-fragments (loop-invariant -> VGPR, 32 regs: 2 x 16 rows this wave)
  const unsigned char* w1b = ws + OFF_W1 + (size_t)n * 32768;
  const unsigned char* w2b = ws + OFF_W2 + (size_t)n * 16384;
  bf16x8 w1f[2][4];
#pragma unroll
  for (int m = 0; m < 2; ++m)
#pragma unroll
    for (int kk = 0; kk < 4; ++kk)
      w1f[m][kk] = gfrag_ld(w1b, wm * 32 + m * 16 + lr, kk * 4 + lk);

  // biases -> LDS stub
  if (tid < 192)
    sBIAS[tid] = (tid < 128) ? rb1[(size_t)n * 128 + tid] : rb2[(size_t)n * 64 + tid - 128];

  // stage SE subtile 0 directly
  stage_f32_tile<512>(se + ((size_t)b0 * 128 + n) * 128, 128 * 128, sSE0, tid, 64);
  unsigned short* outus = reinterpret_cast<unsigned short*>(out3);

  // per-iter tmp flush: 8 threads per b-row, 16B each -> full 128B contiguous line.
  const int fb = tid >> 3, fqt = tid & 7;
  auto flush_out = [&](int tt) {
    uint4 v0 = *reinterpret_cast<const uint4*>(sOUT + fb * 144 + fqt * 16);
    unsigned short* dst = outus + (size_t)(b0 + tt * 64 + fb) * 16384 + 8192 + n * 64 + fqt * 8;
    *reinterpret_cast<uint4*>(dst) = v0;
  };

  float4 fra[2], frb[2];  // next-tile staging registers (2 chunks x 32B, 512 threads)
  {  // prologue: issue loads for tile 1 (consumed at wpref of t=0)
    const float* sb = se + ((size_t)(b0 + 64) * 128 + n) * 128;
#pragma unroll
    for (int k = 0; k < 2; ++k) {
      int c = tid + k * 512;
      int row = c >> 4, s = c & 15;
      const float* p = sb + (size_t)row * 16384 + s * 8;
      fra[k] = *reinterpret_cast<const float4*>(p);
      frb[k] = *reinterpret_cast<const float4*>(p + 4);
    }
  }
  bar_lds();  // tile 0 + biases staged (no vmcnt drain: tile-1 loads stay in flight)

#pragma unroll 1
  for (int t = 0; t < 8; ++t) {
    unsigned char* bufc = (t & 1) ? sSE1 : sSE0;
    unsigned char* bufn = (t & 1) ? sSE0 : sSE1;

    // GEMM1': 128(h_out) x 64(b) x 128(k); wave owns 32 x 32
    f32x4 acc[2][2] = {};
#pragma unroll
    for (int kk = 0; kk < 4; ++kk) {
      const int slot = kk * 4 + lk;
      bf16x8 bv[2];
#pragma unroll
      for (int q = 0; q < 2; ++q) bv[q] = frag_ld(bufc, wq * 32 + q * 16 + lr, slot);
#pragma unroll
      for (int m = 0; m < 2; ++m)
#pragma unroll
        for (int q = 0; q < 2; ++q)
          acc[m][q] = __builtin_amdgcn_mfma_f32_16x16x32_bf16(w1f[m][kk], bv[q], acc[m][q], 0, 0, 0);
    }
    bar_lds();  // [C] all G1 reads of bufc done (SE consumed); prev G2's bufc reads done;
                //     prev epi2's sOUT writes visible

    // flush previous tile's output from sOUT (reads sealed from epi2(t) by [F](t))
    if (t > 0) flush_out(t - 1);

    // write prefetched SE(t+1) into bufn (frees fra/frb early)
    if (t < 7) {
#pragma unroll
      for (int k = 0; k < 2; ++k) {
        int c = tid + k * 512;
        int row = c >> 4, s = c & 15;
        union { unsigned short u[8]; uint4 v; } pk;
#pragma unroll
        for (int j = 0; j < 4; ++j) pk.u[j] = f2bf(fra[k][j]);
#pragma unroll
        for (int j = 0; j < 4; ++j) pk.u[4 + j] = f2bf(frb[k][j]);
        *reinterpret_cast<uint4*>(bufn + row * 256 + ((s ^ (row & 7)) << 4)) = pk.v;
      }
    }
    // issue loads for tile t+2 (consumed at wpref(t+1); crosses two non-draining barriers)
    if (t < 6) {
      const float* sb = se + ((size_t)(b0 + (t + 2) * 64) * 128 + n) * 128;
#pragma unroll
      for (int k = 0; k < 2; ++k) {
        int c = tid + k * 512;
        int row = c >> 4, s = c & 15;
        const float* p = sb + (size_t)row * 16384 + s * 8;
        fra[k] = *reinterpret_cast<const float4*>(p);
        frb[k] = *reinterpret_cast<const float4*>(p + 4);
      }
    }
    // W2 A-fragments: re-read from L2 each iter (same addr -> hot); used after [F]
    bf16x8 w2f[4];
#pragma unroll
    for (int kk = 0; kk < 4; ++kk)
      w2f[kk] = gfrag_ld(w2b, wm * 16 + lr, kk * 4 + lk);

    // epilogue1: hn[b][k] = relu(C1t[k][b] + rb1[k]) -> bf16 IN PLACE into bufc
    // (SE fully consumed at [C]; same row/swizzle scheme as SE layout)
    // lane: b = wq*32+q*16+lr, k = wm*32+m*16+lk*4+j
#pragma unroll
    for (int m = 0; m < 2; ++m) {
      const int k0 = wm * 32 + m * 16 + lk * 4;
      const int s16 = k0 >> 3, half = (k0 >> 2) & 1;
      union { float4 v; float f[4]; } b1;
      b1.v = *reinterpret_cast<const float4*>(sBIAS + k0);
#pragma unroll
      for (int q = 0; q < 2; ++q) {
        const int b = wq * 32 + q * 16 + lr;
        union { unsigned short u[4]; uint2 v; } pk;
#pragma unroll
        for (int j = 0; j < 4; ++j) {
          float v = acc[m][q][j] + b1.f[j];
          v = v > 0.f ? v : 0.f;
          pk.u[j] = f2bf(v);
        }
        *reinterpret_cast<uint2*>(bufc + b * 256 + ((s16 ^ (b & 7)) << 4) + half * 8) = pk.v;
      }
    }
    bar_lds();  // [F] hn (in bufc) + SE(t+1) (in bufn) ready; flush(t-1) reads sealed

    // GEMM2': 64(w) x 64(b) x 128(k); wave owns 16 x 32; hn read from bufc
    f32x4 acc2[2] = {};
#pragma unroll
    for (int kk = 0; kk < 4; ++kk) {
      const int slot = kk * 4 + lk;
      bf16x8 bv[2];
#pragma unroll
      for (int q = 0; q < 2; ++q) bv[q] = frag_ld(bufc, wq * 32 + q * 16 + lr, slot);
#pragma unroll
      for (int q = 0; q < 2; ++q)
        acc2[q] = __builtin_amdgcn_mfma_f32_16x16x32_bf16(w2f[kk], bv[q], acc2[q], 0, 0, 0);
    }

    // epilogue2: bf16 into sOUT[b][w] (padded rows 144B); w = wm*16+lk*4+j
    {
      const int w0 = wm * 16 + lk * 4;
      union { float4 v; float f[4]; } b2;
      b2.v = *reinterpret_cast<const float4*>(sBIAS + 128 + w0);
#pragma unroll
      for (int q = 0; q < 2; ++q) {
        const int bloc = wq * 32 + q * 16 + lr;
        union { unsigned short u[4]; uint2 v; } pk;
#pragma unroll
        for (int j = 0; j < 4; ++j) pk.u[j] = f2bf(acc2[q][j] + b2.f[j]);
        *reinterpret_cast<uint2*>(sOUT + bloc * 144 + w0 * 2) = pk.v;
      }
    }
    // no closing barrier: G2(t) r:bufc vs wpref(t+1) w:bufc split by [C](t+1);
    // epi2(t) w:sOUT vs flush(t) r:sOUT split by [C](t+1).
  }
  bar_lds();       // seal epi2(7)'s sOUT writes
  flush_out(7);    // final tile flush
}

// ================ K3: transpose (4096 blocks) || f2 (192 blocks) ================
__global__ __launch_bounds__(256) void transpose_f2_kernel(float* __restrict__ out3,
                                                           const unsigned char* __restrict__ ws,
                                                           const float* __restrict__ fc2b,
                                                           float* __restrict__ out2) {
  __shared__ unsigned char smem[32768];
  const int bid = blockIdx.x;
  const int tid = threadIdx.x;
  const int wave = tid >> 6, lane = tid & 63;

  if (bid >= 4096) {
    // ---- f2 path: 192 blocks (bt 0..63 x ch 0..2), 64 b-rows each ----
    const int fid = bid - 4096;
    const int bt = fid & 63, ch = fid >> 6;
    const int b0 = bt * 64;
    const int lr = lane & 15, lk = lane >> 4;
    unsigned char* sB = smem;  // 32KB F2s chunk
    {
      const uint4* bp = reinterpret_cast<const uint4*>(ws + OFF_F2 + (size_t)ch * 32768);
      uint4* db = reinterpret_cast<uint4*>(sB);
      for (int c = tid; c < 2048; c += 256) db[c] = bp[c];
    }
    __syncthreads();

    const int wm = wave >> 1, wn = wave & 1;
    const unsigned char* htile = ws + OFF_H + (size_t)bt * 16384;

    f32x4 acc[2][4] = {};
#pragma unroll
    for (int kk = 0; kk < 4; ++kk) {
      const int slot = kk * 4 + lk;
      bf16x8 af[2], bfv[4];
#pragma unroll
      for (int m = 0; m < 2; ++m) af[m] = frag_ld(htile, wm * 32 + m * 16 + lr, slot);
#pragma unroll
      for (int q = 0; q < 4; ++q) bfv[q] = frag_ld(sB, wn * 64 + q * 16 + lr, slot);
#pragma unroll
      for (int m = 0; m < 2; ++m)
#pragma unroll
        for (int q = 0; q < 4; ++q)
          acc[m][q] = __builtin_amdgcn_mfma_f32_16x16x32_bf16(af[m], bfv[q], acc[m][q], 0, 0, 0);
    }

#pragma unroll
    for (int q = 0; q < 4; ++q) {
      int o = ch * 128 + wn * 64 + q * 16 + lr;
      float bias = fc2b[o];
#pragma unroll
      for (int m = 0; m < 2; ++m) {
#pragma unroll
        for (int j = 0; j < 4; ++j) {
          int r = wm * 32 + m * 16 + lk * 4 + j;
          out2[(size_t)(b0 + r) * 384 + o] = acc[m][q][j] + bias;
        }
      }
    }
    return;
  }

  // ---- transpose path: tmp bf16 [b][n][w] -> out3 fp32 [b][w][n], LDS-free ----
  const int b = bid;
  const unsigned short* t = reinterpret_cast<const unsigned short*>(out3) + (size_t)b * 16384 + 8192;
  float* dst = out3 + (size_t)b * 8192;
  uint4 r[2][2];
#pragma unroll
  for (int half = 0; half < 2; ++half) {
    const int g = half * 4 + wave;
    r[half][0] = *reinterpret_cast<const uint4*>(t + lane * 64 + g * 8);
    r[half][1] = *reinterpret_cast<const uint4*>(t + (size_t)(lane + 64) * 64 + g * 8);
  }
  __syncthreads();  // all reads done before dst writes clobber the tmp region
#pragma unroll
  for (int half = 0; half < 2; ++half) {
    const int g = half * 4 + wave;
    union { uint4 v; unsigned short u[8]; } p0, p1;
    p0.v = r[half][0];
    p1.v = r[half][1];
#pragma unroll
    for (int j = 0; j < 8; ++j) {
      dst[(g * 8 + j) * 128 + lane] = bf2f(p0.u[j]);
      dst[(g * 8 + j) * 128 + lane + 64] = bf2f(p1.u[j]);
    }
  }
}

extern "C" void kernel_launch(void* const* d_in, const int* in_sizes, int n_in,
                              void* d_out, int out_size, void* d_ws, size_t ws_size,
                              hipStream_t stream) {
  const float* emb  = (const float*)d_in[0];
  const float* se   = (const float*)d_in[1];
  const float* slog = (const float*)d_in[2];
  const float* fc1w = (const float*)d_in[3];
  const float* fc1b = (const float*)d_in[4];
  const float* fc2w = (const float*)d_in[5];
  const float* fc2b = (const float*)d_in[6];
  const float* rw1  = (const float*)d_in[7];
  const float* rb1  = (const float*)d_in[8];
  const float* rw2  = (const float*)d_in[9];
  const float* rb2  = (const float*)d_in[10];
  float* out = (float*)d_out;
  unsigned char* ws = (unsigned char*)d_ws;

  float* out2 = out + (size_t)B_SZ * N_SZ;
  float* out3 = out2 + (size_t)B_SZ * 384;

  // K1: weight prep + logits copy || forecast stage 1
  prep_f1_kernel<<<2136, 256, 0, stream>>>(rw1, rw2, fc2w, slog, emb, fc1w, fc1b, out, ws);

  // K2: reconstruction, 512-thread blocks, 42.75KB LDS (3 blocks/CU if VGPR allows)
  recon_kernel<<<1024, 512, 0, stream>>>(se, rb1, rb2, ws, out3);

  // K3: transpose to final [b][w][n] fp32 || forecast stage 2
  transpose_f2_kernel<<<4288, 256, 0, stream>>>(out3, ws, fc2b, out2);
}

// Round 18
// 124.205 us; speedup vs baseline: 1.1079x; 1.0505x over previous
//
#include <hip/hip_runtime.h>
#include <hip/hip_bf16.h>
#include <stdint.h>

typedef __attribute__((ext_vector_type(8))) short bf16x8;
typedef __attribute__((ext_vector_type(4))) float f32x4;

#define DEVI static __device__ __forceinline__

// Problem sizes (fixed)
static constexpr int B_SZ = 4096, N_SZ = 128, H_SZ = 128, W_SZ = 64;

// ws layout (bytes), all 16B aligned
static constexpr size_t OFF_W1 = 0;                      // 128 * 128*128 bf16 = 4 MB (UNswizzled [n][c][h])
static constexpr size_t OFF_W2 = OFF_W1 + 4194304;       // 128 * 64*128 bf16 = 2 MB (UNswizzled [n][w][k])
static constexpr size_t OFF_F1 = OFF_W2 + 2097152;       // (unused)
static constexpr size_t OFF_F2 = OFF_F1 + 32768;         // 384*128 bf16 = 96 KB (swizzled [o][j])
static constexpr size_t OFF_H  = OFF_F2 + 98304;         // 64 tiles x 16KB bf16 (swizzled 64-row h tiles)

DEVI unsigned short f2bf(float f) {
  union { __hip_bfloat16 b; unsigned short u; } cv;
  cv.b = __float2bfloat16(f);
  return cv.u;
}
DEVI float bf2f(unsigned short u) {
  union { unsigned int i; float f; } cv;
  cv.i = ((unsigned int)u) << 16;
  return cv.f;
}

// Raw workgroup barrier: execution sync + LDS visibility (lgkmcnt), but does NOT
// drain vmcnt -> global prefetch loads stay in flight across it.
DEVI void bar_lds() {
  __builtin_amdgcn_sched_barrier(0);
  asm volatile("s_waitcnt lgkmcnt(0)" ::: "memory");
  __builtin_amdgcn_s_barrier();
  __builtin_amdgcn_sched_barrier(0);
}

// Read one MFMA fragment (8 contiguous bf16 along k) from a swizzled tile
// (LDS or global). Row stride 256B; 16B slot s stored at (s ^ (row&7)).
DEVI bf16x8 frag_ld(const unsigned char* base, int row, int kslot) {
  return *reinterpret_cast<const bf16x8*>(base + row * 256 + (((kslot ^ (row & 7)) << 4)));
}
// Unswizzled fragment read (global memory, 256B rows).
DEVI bf16x8 gfrag_ld(const unsigned char* base, int row, int kslot) {
  return *reinterpret_cast<const bf16x8*>(base + row * 256 + (kslot << 4));
}

// Stage an nrows x 128 fp32 tile (row stride in elems) into swizzled bf16 LDS.
template <int NT>
DEVI void stage_f32_tile(const float* src, int row_stride, unsigned char* dst, int tid, int nrows) {
  for (int t = tid; t < nrows * 16; t += NT) {
    int row = t >> 4, s = t & 15;
    const float* p = src + (size_t)row * row_stride + s * 8;
    union { unsigned short u[8]; uint4 v; } pk;
#pragma unroll
    for (int j = 0; j < 8; ++j) pk.u[j] = f2bf(p[j]);
    *reinterpret_cast<uint4*>(dst + row * 256 + ((s ^ (row & 7)) << 4)) = pk.v;
  }
}

// ================ K1: prep (W1,W2,F2s,logits) || f1 (h = relu(emb@fc1^T+b1)) ================
__global__ __launch_bounds__(256) void prep_f1_kernel(const float* __restrict__ rw1,
                                                      const float* __restrict__ rw2,
                                                      const float* __restrict__ fc2w,
                                                      const float* __restrict__ slog,
                                                      const float* __restrict__ emb,
                                                      const float* __restrict__ fc1w,
                                                      const float* __restrict__ fc1b,
                                                      float* __restrict__ out,
                                                      unsigned char* __restrict__ ws) {
  __shared__ unsigned char sA[16384];  // f1: emb 64-row tile
  __shared__ unsigned char sB[32768];  // f1: fc1w tile

  const int bid = blockIdx.x;
  const int tid = threadIdx.x;
  if (bid < 2072) {
    const int T_W1 = 128 * 128 * 16;  // (n,s,c): W1t[n][c][h=s*8+j] = rw1[n][h][c]
    const int T_W2 = 128 * 64 * 16;   // (n,s,w): W2t[n][w][k=s*8+j] = rw2[n][k][w]
    const int T_F2 = 384 * 16;        // (o,s):   F2s[o][j] = fc2w[o][j]  (swizzled)
    int id = bid * 256 + tid;
    if (id < T_W1) {
      int c = id & 127, rest = id >> 7;
      int s = rest & 15, n = rest >> 4;
      const float* src = rw1 + (size_t)n * 16384 + (size_t)(s * 8) * 128 + c;
      union { unsigned short u[8]; uint4 v; } pk;
#pragma unroll
      for (int j = 0; j < 8; ++j) pk.u[j] = f2bf(src[(size_t)j * 128]);
      size_t dst = OFF_W1 + ((size_t)n * 128 + c) * 256 + (size_t)(s << 4);
      *reinterpret_cast<uint4*>(ws + dst) = pk.v;
      return;
    }
    id -= T_W1;
    if (id < T_W2) {
      int w = id & 63, rest = id >> 6;
      int s = rest & 15, n = rest >> 4;
      const float* src = rw2 + (size_t)n * 8192 + (size_t)(s * 8) * 64 + w;
      union { unsigned short u[8]; uint4 v; } pk;
#pragma unroll
      for (int j = 0; j < 8; ++j) pk.u[j] = f2bf(src[(size_t)j * 64]);
      size_t dst = OFF_W2 + ((size_t)n * 64 + w) * 256 + (size_t)(s << 4);
      *reinterpret_cast<uint4*>(ws + dst) = pk.v;
      return;
    }
    id -= T_W2;
    if (id < T_F2) {
      int s = id & 15, o = id >> 4;
      const float* src = fc2w + (size_t)o * 128 + s * 8;
      union { unsigned short u[8]; uint4 v; } pk;
#pragma unroll
      for (int j = 0; j < 8; ++j) pk.u[j] = f2bf(src[j]);
      *reinterpret_cast<uint4*>(ws + OFF_F2 + (size_t)o * 256 + ((s ^ (o & 7)) << 4)) = pk.v;
      return;
    }
    id -= T_F2;
    // logits passthrough: 2MB as uint4
    reinterpret_cast<uint4*>(out)[id] = reinterpret_cast<const uint4*>(slog)[id];
    return;
  }

  // ---- f1 path: 64 blocks x 64 b-rows ----
  const int bt = bid - 2072;
  const int b0 = bt * 64;
  stage_f32_tile<256>(fc1w, 128, sB, tid, 128);
  stage_f32_tile<256>(emb + (size_t)b0 * 128, 128, sA, tid, 64);
  __syncthreads();

  const int wave = tid >> 6, lane = tid & 63;
  const int wm = wave >> 1, wn = wave & 1;
  const int lr = lane & 15, lk = lane >> 4;

  f32x4 acc[2][4] = {};
#pragma unroll
  for (int kk = 0; kk < 4; ++kk) {
    const int slot = kk * 4 + lk;
    bf16x8 af[2], bfv[4];
#pragma unroll
    for (int m = 0; m < 2; ++m) af[m] = frag_ld(sA, wm * 32 + m * 16 + lr, slot);
#pragma unroll
    for (int q = 0; q < 4; ++q) bfv[q] = frag_ld(sB, wn * 64 + q * 16 + lr, slot);
#pragma unroll
    for (int m = 0; m < 2; ++m)
#pragma unroll
      for (int q = 0; q < 4; ++q)
        acc[m][q] = __builtin_amdgcn_mfma_f32_16x16x32_bf16(af[m], bfv[q], acc[m][q], 0, 0, 0);
  }

  unsigned char* tile = ws + OFF_H + (size_t)bt * 16384;
#pragma unroll
  for (int q = 0; q < 4; ++q) {
    int c = wn * 64 + q * 16 + lr;
    float bias = fc1b[c];
#pragma unroll
    for (int m = 0; m < 2; ++m) {
#pragma unroll
      for (int j = 0; j < 4; ++j) {
        int r = wm * 32 + m * 16 + lk * 4 + j;
        float v = acc[m][q][j] + bias;
        v = v > 0.f ? v : 0.f;
        *reinterpret_cast<unsigned short*>(tile + r * 256 + ((c * 2) ^ ((r & 7) << 4))) = f2bf(v);
      }
    }
  }
}

// ================ K2: recon, 512 blocks x 16 tiles = single occupancy round ================
// v17 inner loop unchanged (8 waves; in-place hn in bufc; sOUT coalesced flush;
// 2 non-draining barriers/iter). Grid halved, per-block work doubled: one cold
// prologue fill instead of two, no inter-round transition, weight loads
// amortized over 16 tiles. s_setprio(1) around MFMA clusters (T5): 2 async
// blocks/CU provide wave role-diversity.
// Hazards (2 non-draining barriers/iter):
//   epi1(t) w:bufc  vs G1(t) r:bufc        -- split by [C](t)
//   G2(t)  r:bufc   vs wpref(t+1) w:bufc   -- split by [C](t+1)
//   wpref(t) w:bufn vs G1(t+1) r:bufn      -- split by [F](t)
//   epi2(t) w:sOUT  vs flush(t) r:sOUT     -- split by [C](t+1)
//   flush(t-1) r:sOUT vs epi2(t) w:sOUT    -- split by [F](t)
__global__ __launch_bounds__(512) void recon_kernel(const float* __restrict__ se,
                                                    const float* __restrict__ rb1,
                                                    const float* __restrict__ rb2,
                                                    const unsigned char* __restrict__ ws,
                                                    float* __restrict__ out3) {
  __shared__ unsigned char smem[43520];

  const int bid = blockIdx.x;
  const int tid = threadIdx.x;
  const int wave = tid >> 6, lane = tid & 63;
  const int lr = lane & 15, lk = lane >> 4;

  unsigned char* sSE0 = smem;                              // 16KB (SE, then hn in place)
  unsigned char* sSE1 = smem + 16384;                      // 16KB
  unsigned char* sOUT = smem + 32768;                      // 64 x 72 bf16 = 9216B (padded rows)
  float* sBIAS = reinterpret_cast<float*>(smem + 41984);   // [0..127] rb1, [128..191] rb2

  const int n = bid & 127;   // linear id % 8 == n % 8 -> same-n blocks share XCD
  const int btg = bid >> 7;  // 0..3
  const int b0 = btg * 1024;

  const int wm = wave >> 1;  // 0..3: G1 h_out 32-row group / G2 w 16-row group
  const int wq = wave & 1;   // 0..1: b half (32 each)

  // W1 A-fragments (loop-invariant -> VGPR, 32 regs: 2 x 16 rows this wave)
  const unsigned char* w1b = ws + OFF_W1 + (size_t)n * 32768;
  const unsigned char* w2b = ws + OFF_W2 + (size_t)n * 16384;
  bf16x8 w1f[2][4];
#pragma unroll
  for (int m = 0; m < 2; ++m)
#pragma unroll
    for (int kk = 0; kk < 4; ++kk)
      w1f[m][kk] = gfrag_ld(w1b, wm * 32 + m * 16 + lr, kk * 4 + lk);

  // biases -> LDS stub
  if (tid < 192)
    sBIAS[tid] = (tid < 128) ? rb1[(size_t)n * 128 + tid] : rb2[(size_t)n * 64 + tid - 128];

  // stage SE subtile 0 directly
  stage_f32_tile<512>(se + ((size_t)b0 * 128 + n) * 128, 128 * 128, sSE0, tid, 64);
  unsigned short* outus = reinterpret_cast<unsigned short*>(out3);

  // per-iter tmp flush: 8 threads per b-row, 16B each -> full 128B contiguous line.
  const int fb = tid >> 3, fqt = tid & 7;
  auto flush_out = [&](int tt) {
    uint4 v0 = *reinterpret_cast<const uint4*>(sOUT + fb * 144 + fqt * 16);
    unsigned short* dst = outus + (size_t)(b0 + tt * 64 + fb) * 16384 + 8192 + n * 64 + fqt * 8;
    *reinterpret_cast<uint4*>(dst) = v0;
  };

  float4 fra[2], frb[2];  // next-tile staging registers (2 chunks x 32B, 512 threads)
  {  // prologue: issue loads for tile 1 (consumed at wpref of t=0)
    const float* sb = se + ((size_t)(b0 + 64) * 128 + n) * 128;
#pragma unroll
    for (int k = 0; k < 2; ++k) {
      int c = tid + k * 512;
      int row = c >> 4, s = c & 15;
      const float* p = sb + (size_t)row * 16384 + s * 8;
      fra[k] = *reinterpret_cast<const float4*>(p);
      frb[k] = *reinterpret_cast<const float4*>(p + 4);
    }
  }
  bar_lds();  // tile 0 + biases staged (no vmcnt drain: tile-1 loads stay in flight)

#pragma unroll 1
  for (int t = 0; t < 16; ++t) {
    unsigned char* bufc = (t & 1) ? sSE1 : sSE0;
    unsigned char* bufn = (t & 1) ? sSE0 : sSE1;

    // GEMM1': 128(h_out) x 64(b) x 128(k); wave owns 32 x 32
    f32x4 acc[2][2] = {};
    __builtin_amdgcn_s_setprio(1);
#pragma unroll
    for (int kk = 0; kk < 4; ++kk) {
      const int slot = kk * 4 + lk;
      bf16x8 bv[2];
#pragma unroll
      for (int q = 0; q < 2; ++q) bv[q] = frag_ld(bufc, wq * 32 + q * 16 + lr, slot);
#pragma unroll
      for (int m = 0; m < 2; ++m)
#pragma unroll
        for (int q = 0; q < 2; ++q)
          acc[m][q] = __builtin_amdgcn_mfma_f32_16x16x32_bf16(w1f[m][kk], bv[q], acc[m][q], 0, 0, 0);
    }
    __builtin_amdgcn_s_setprio(0);
    bar_lds();  // [C] all G1 reads of bufc done (SE consumed); prev G2's bufc reads done;
                //     prev epi2's sOUT writes visible

    // flush previous tile's output from sOUT (reads sealed from epi2(t) by [F](t))
    if (t > 0) flush_out(t - 1);

    // write prefetched SE(t+1) into bufn (frees fra/frb early)
    if (t < 15) {
#pragma unroll
      for (int k = 0; k < 2; ++k) {
        int c = tid + k * 512;
        int row = c >> 4, s = c & 15;
        union { unsigned short u[8]; uint4 v; } pk;
#pragma unroll
        for (int j = 0; j < 4; ++j) pk.u[j] = f2bf(fra[k][j]);
#pragma unroll
        for (int j = 0; j < 4; ++j) pk.u[4 + j] = f2bf(frb[k][j]);
        *reinterpret_cast<uint4*>(bufn + row * 256 + ((s ^ (row & 7)) << 4)) = pk.v;
      }
    }
    // issue loads for tile t+2 (consumed at wpref(t+1); crosses two non-draining barriers)
    if (t < 14) {
      const float* sb = se + ((size_t)(b0 + (t + 2) * 64) * 128 + n) * 128;
#pragma unroll
      for (int k = 0; k < 2; ++k) {
        int c = tid + k * 512;
        int row = c >> 4, s = c & 15;
        const float* p = sb + (size_t)row * 16384 + s * 8;
        fra[k] = *reinterpret_cast<const float4*>(p);
        frb[k] = *reinterpret_cast<const float4*>(p + 4);
      }
    }
    // W2 A-fragments: re-read from L2 each iter (same addr -> hot); used after [F]
    bf16x8 w2f[4];
#pragma unroll
    for (int kk = 0; kk < 4; ++kk)
      w2f[kk] = gfrag_ld(w2b, wm * 16 + lr, kk * 4 + lk);

    // epilogue1: hn[b][k] = relu(C1t[k][b] + rb1[k]) -> bf16 IN PLACE into bufc
    // (SE fully consumed at [C]; same row/swizzle scheme as SE layout)
    // lane: b = wq*32+q*16+lr, k = wm*32+m*16+lk*4+j
#pragma unroll
    for (int m = 0; m < 2; ++m) {
      const int k0 = wm * 32 + m * 16 + lk * 4;
      const int s16 = k0 >> 3, half = (k0 >> 2) & 1;
      union { float4 v; float f[4]; } b1;
      b1.v = *reinterpret_cast<const float4*>(sBIAS + k0);
#pragma unroll
      for (int q = 0; q < 2; ++q) {
        const int b = wq * 32 + q * 16 + lr;
        union { unsigned short u[4]; uint2 v; } pk;
#pragma unroll
        for (int j = 0; j < 4; ++j) {
          float v = acc[m][q][j] + b1.f[j];
          v = v > 0.f ? v : 0.f;
          pk.u[j] = f2bf(v);
        }
        *reinterpret_cast<uint2*>(bufc + b * 256 + ((s16 ^ (b & 7)) << 4) + half * 8) = pk.v;
      }
    }
    bar_lds();  // [F] hn (in bufc) + SE(t+1) (in bufn) ready; flush(t-1) reads sealed

    // GEMM2': 64(w) x 64(b) x 128(k); wave owns 16 x 32; hn read from bufc
    f32x4 acc2[2] = {};
    __builtin_amdgcn_s_setprio(1);
#pragma unroll
    for (int kk = 0; kk < 4; ++kk) {
      const int slot = kk * 4 + lk;
      bf16x8 bv[2];
#pragma unroll
      for (int q = 0; q < 2; ++q) bv[q] = frag_ld(bufc, wq * 32 + q * 16 + lr, slot);
#pragma unroll
      for (int q = 0; q < 2; ++q)
        acc2[q] = __builtin_amdgcn_mfma_f32_16x16x32_bf16(w2f[kk], bv[q], acc2[q], 0, 0, 0);
    }
    __builtin_amdgcn_s_setprio(0);

    // epilogue2: bf16 into sOUT[b][w] (padded rows 144B); w = wm*16+lk*4+j
    {
      const int w0 = wm * 16 + lk * 4;
      union { float4 v; float f[4]; } b2;
      b2.v = *reinterpret_cast<const float4*>(sBIAS + 128 + w0);
#pragma unroll
      for (int q = 0; q < 2; ++q) {
        const int bloc = wq * 32 + q * 16 + lr;
        union { unsigned short u[4]; uint2 v; } pk;
#pragma unroll
        for (int j = 0; j < 4; ++j) pk.u[j] = f2bf(acc2[q][j] + b2.f[j]);
        *reinterpret_cast<uint2*>(sOUT + bloc * 144 + w0 * 2) = pk.v;
      }
    }
    // no closing barrier: G2(t) r:bufc vs wpref(t+1) w:bufc split by [C](t+1);
    // epi2(t) w:sOUT vs flush(t) r:sOUT split by [C](t+1).
  }
  bar_lds();       // seal epi2(15)'s sOUT writes
  flush_out(15);   // final tile flush
}

// ================ K3: transpose (4096 blocks) || f2 (192 blocks) ================
__global__ __launch_bounds__(256) void transpose_f2_kernel(float* __restrict__ out3,
                                                           const unsigned char* __restrict__ ws,
                                                           const float* __restrict__ fc2b,
                                                           float* __restrict__ out2) {
  __shared__ unsigned char smem[32768];
  const int bid = blockIdx.x;
  const int tid = threadIdx.x;
  const int wave = tid >> 6, lane = tid & 63;

  if (bid >= 4096) {
    // ---- f2 path: 192 blocks (bt 0..63 x ch 0..2), 64 b-rows each ----
    const int fid = bid - 4096;
    const int bt = fid & 63, ch = fid >> 6;
    const int b0 = bt * 64;
    const int lr = lane & 15, lk = lane >> 4;
    unsigned char* sB = smem;  // 32KB F2s chunk
    {
      const uint4* bp = reinterpret_cast<const uint4*>(ws + OFF_F2 + (size_t)ch * 32768);
      uint4* db = reinterpret_cast<uint4*>(sB);
      for (int c = tid; c < 2048; c += 256) db[c] = bp[c];
    }
    __syncthreads();

    const int wm = wave >> 1, wn = wave & 1;
    const unsigned char* htile = ws + OFF_H + (size_t)bt * 16384;

    f32x4 acc[2][4] = {};
#pragma unroll
    for (int kk = 0; kk < 4; ++kk) {
      const int slot = kk * 4 + lk;
      bf16x8 af[2], bfv[4];
#pragma unroll
      for (int m = 0; m < 2; ++m) af[m] = frag_ld(htile, wm * 32 + m * 16 + lr, slot);
#pragma unroll
      for (int q = 0; q < 4; ++q) bfv[q] = frag_ld(sB, wn * 64 + q * 16 + lr, slot);
#pragma unroll
      for (int m = 0; m < 2; ++m)
#pragma unroll
        for (int q = 0; q < 4; ++q)
          acc[m][q] = __builtin_amdgcn_mfma_f32_16x16x32_bf16(af[m], bfv[q], acc[m][q], 0, 0, 0);
    }

#pragma unroll
    for (int q = 0; q < 4; ++q) {
      int o = ch * 128 + wn * 64 + q * 16 + lr;
      float bias = fc2b[o];
#pragma unroll
      for (int m = 0; m < 2; ++m) {
#pragma unroll
        for (int j = 0; j < 4; ++j) {
          int r = wm * 32 + m * 16 + lk * 4 + j;
          out2[(size_t)(b0 + r) * 384 + o] = acc[m][q][j] + bias;
        }
      }
    }
    return;
  }

  // ---- transpose path: tmp bf16 [b][n][w] -> out3 fp32 [b][w][n], LDS-free ----
  const int b = bid;
  const unsigned short* t = reinterpret_cast<const unsigned short*>(out3) + (size_t)b * 16384 + 8192;
  float* dst = out3 + (size_t)b * 8192;
  uint4 r[2][2];
#pragma unroll
  for (int half = 0; half < 2; ++half) {
    const int g = half * 4 + wave;
    r[half][0] = *reinterpret_cast<const uint4*>(t + lane * 64 + g * 8);
    r[half][1] = *reinterpret_cast<const uint4*>(t + (size_t)(lane + 64) * 64 + g * 8);
  }
  __syncthreads();  // all reads done before dst writes clobber the tmp region
#pragma unroll
  for (int half = 0; half < 2; ++half) {
    const int g = half * 4 + wave;
    union { uint4 v; unsigned short u[8]; } p0, p1;
    p0.v = r[half][0];
    p1.v = r[half][1];
#pragma unroll
    for (int j = 0; j < 8; ++j) {
      dst[(g * 8 + j) * 128 + lane] = bf2f(p0.u[j]);
      dst[(g * 8 + j) * 128 + lane + 64] = bf2f(p1.u[j]);
    }
  }
}

extern "C" void kernel_launch(void* const* d_in, const int* in_sizes, int n_in,
                              void* d_out, int out_size, void* d_ws, size_t ws_size,
                              hipStream_t stream) {
  const float* emb  = (const float*)d_in[0];
  const float* se   = (const float*)d_in[1];
  const float* slog = (const float*)d_in[2];
  const float* fc1w = (const float*)d_in[3];
  const float* fc1b = (const float*)d_in[4];
  const float* fc2w = (const float*)d_in[5];
  const float* fc2b = (const float*)d_in[6];
  const float* rw1  = (const float*)d_in[7];
  const float* rb1  = (const float*)d_in[8];
  const float* rw2  = (const float*)d_in[9];
  const float* rb2  = (const float*)d_in[10];
  float* out = (float*)d_out;
  unsigned char* ws = (unsigned char*)d_ws;

  float* out2 = out + (size_t)B_SZ * N_SZ;
  float* out3 = out2 + (size_t)B_SZ * 384;

  // K1: weight prep + logits copy || forecast stage 1
  prep_f1_kernel<<<2136, 256, 0, stream>>>(rw1, rw2, fc2w, slog, emb, fc1w, fc1b, out, ws);

  // K2: reconstruction, 512 blocks x 16 tiles (single occupancy round)
  recon_kernel<<<512, 512, 0, stream>>>(se, rb1, rb2, ws, out3);

  // K3: transpose to final [b][w][n] fp32 || forecast stage 2
  transpose_f2_kernel<<<4288, 256, 0, stream>>>(out3, ws, fc2b, out2);
}